// Round 14
// baseline (209.465 us; speedup 1.0000x reference)
//
#include <hip/hip_runtime.h>
#include <hip/hip_bf16.h>
#include <math.h>

// Problem constants (B=1)
#define S_LEN 2048
#define D_DIM 512
#define H_NUM 8
#define HD    64
#define C_NUM 32
#define TOPK  5
#define SCALE 0.125f   // hd^-0.5
#define QCAP  1024     // fixed qlist capacity per (h,c); load is ~320
#define ATILES 16      // query tiles per (h,c); empties exit fast

typedef __attribute__((ext_vector_type(8))) short bf16x8;   // 8 bf16 (4 VGPRs)
typedef __attribute__((ext_vector_type(4))) float f32x4;
typedef __attribute__((ext_vector_type(4))) unsigned short us4;

__device__ __forceinline__ unsigned short f2b(float f) {
    __hip_bfloat16 h = __float2bfloat16(f);
    unsigned short u;
    __builtin_memcpy(&u, &h, 2);
    return u;
}
__device__ __forceinline__ bf16x8 pack8(float4 a, float4 b) {
    bf16x8 r;
    r[0] = (short)f2b(a.x); r[1] = (short)f2b(a.y);
    r[2] = (short)f2b(a.z); r[3] = (short)f2b(a.w);
    r[4] = (short)f2b(b.x); r[5] = (short)f2b(b.y);
    r[6] = (short)f2b(b.z); r[7] = (short)f2b(b.w);
    return r;
}
__device__ __forceinline__ float b2f(unsigned short u) {
    __hip_bfloat16 h;
    __builtin_memcpy(&h, &u, 2);
    return __bfloat162float(h);
}

// ---------------------------------------------------------------------------
// Dual-output fp32 GEMM: one block computes the 64x64 Q-tile AND K-tile
// from a single staged A tile. Per-element FMA chains remain k-ascending
// fma(a,b,acc) -> BIT-IDENTICAL Q/K values to rounds 7-13 (routing safety).
// LDS traffic per FMA drops 1.5x vs separate Q/K blocks (the measured
// bottleneck: VALUBusy 44%, at the ds_read floor).
// ---------------------------------------------------------------------------
#define BM 64
#define BN 64
#define BK 32

__global__ __launch_bounds__(256) void gemm_qk2(const float* __restrict__ A,
                                                const float* __restrict__ Wq,
                                                const float* __restrict__ Wk,
                                                float* __restrict__ Qb,
                                                float* __restrict__ Kb) {
    __shared__ float As[BK][BM + 4];
    __shared__ float Bq[BK][BN];
    __shared__ float Bk[BK][BN];

    const int t  = threadIdx.x;
    const int tx = t & 15;
    const int ty = t >> 4;
    const int m0 = blockIdx.y * BM;
    const int n0 = blockIdx.x * BN;
    const int N = D_DIM, K = D_DIM;

    float4 q0 = make_float4(0.f,0.f,0.f,0.f), q1 = q0, q2 = q0, q3 = q0;
    float4 k0a = q0, k1a = q0, k2a = q0, k3a = q0;

    const int ar = t >> 3;        // 0..31
    const int ac = (t & 7) * 4;   // 0..28
    const int br = t >> 4;        // 0..15
    const int bc = (t & 15) * 4;  // 0..60

    float4 a0, a1, bq0, bq1, bk0, bk1;
    auto LD = [&](int k0) {
        a0  = *(const float4*)&A [(size_t)(m0 + ar)      * K + k0 + ac];
        a1  = *(const float4*)&A [(size_t)(m0 + ar + 32) * K + k0 + ac];
        bq0 = *(const float4*)&Wq[(size_t)(k0 + br)      * N + n0 + bc];
        bq1 = *(const float4*)&Wq[(size_t)(k0 + br + 16) * N + n0 + bc];
        bk0 = *(const float4*)&Wk[(size_t)(k0 + br)      * N + n0 + bc];
        bk1 = *(const float4*)&Wk[(size_t)(k0 + br + 16) * N + n0 + bc];
    };

    LD(0);
    for (int k0 = 0; k0 < K; k0 += BK) {
        __syncthreads();
        As[ac+0][ar]    = a0.x; As[ac+1][ar]    = a0.y; As[ac+2][ar]    = a0.z; As[ac+3][ar]    = a0.w;
        As[ac+0][ar+32] = a1.x; As[ac+1][ar+32] = a1.y; As[ac+2][ar+32] = a1.z; As[ac+3][ar+32] = a1.w;
        *(float4*)&Bq[br][bc]      = bq0;
        *(float4*)&Bq[br + 16][bc] = bq1;
        *(float4*)&Bk[br][bc]      = bk0;
        *(float4*)&Bk[br + 16][bc] = bk1;
        __syncthreads();

        if (k0 + BK < K) LD(k0 + BK);

        #pragma unroll
        for (int kk = 0; kk < BK; ++kk) {
            float4 a  = *(const float4*)&As[kk][ty * 4];
            float4 b  = *(const float4*)&Bq[kk][tx * 4];
            float4 bk = *(const float4*)&Bk[kk][tx * 4];
            q0.x += a.x*b.x; q0.y += a.x*b.y; q0.z += a.x*b.z; q0.w += a.x*b.w;
            q1.x += a.y*b.x; q1.y += a.y*b.y; q1.z += a.y*b.z; q1.w += a.y*b.w;
            q2.x += a.z*b.x; q2.y += a.z*b.y; q2.z += a.z*b.z; q2.w += a.z*b.w;
            q3.x += a.w*b.x; q3.y += a.w*b.y; q3.z += a.w*b.z; q3.w += a.w*b.w;
            k0a.x += a.x*bk.x; k0a.y += a.x*bk.y; k0a.z += a.x*bk.z; k0a.w += a.x*bk.w;
            k1a.x += a.y*bk.x; k1a.y += a.y*bk.y; k1a.z += a.y*bk.z; k1a.w += a.y*bk.w;
            k2a.x += a.z*bk.x; k2a.y += a.z*bk.y; k2a.z += a.z*bk.z; k2a.w += a.z*bk.w;
            k3a.x += a.w*bk.x; k3a.y += a.w*bk.y; k3a.z += a.w*bk.z; k3a.w += a.w*bk.w;
        }
    }

    *(float4*)&Qb[(size_t)(m0 + ty*4 + 0) * N + n0 + tx*4] = q0;
    *(float4*)&Qb[(size_t)(m0 + ty*4 + 1) * N + n0 + tx*4] = q1;
    *(float4*)&Qb[(size_t)(m0 + ty*4 + 2) * N + n0 + tx*4] = q2;
    *(float4*)&Qb[(size_t)(m0 + ty*4 + 3) * N + n0 + tx*4] = q3;
    *(float4*)&Kb[(size_t)(m0 + ty*4 + 0) * N + n0 + tx*4] = k0a;
    *(float4*)&Kb[(size_t)(m0 + ty*4 + 1) * N + n0 + tx*4] = k1a;
    *(float4*)&Kb[(size_t)(m0 + ty*4 + 2) * N + n0 + tx*4] = k2a;
    *(float4*)&Kb[(size_t)(m0 + ty*4 + 3) * N + n0 + tx*4] = k3a;
}

// ---------------------------------------------------------------------------
// bf16 MFMA GEMM body for the V projection (fp32 A, fp32 B, bf16 C).
// Fragments per R11-verified layouts.
// ---------------------------------------------------------------------------
__device__ __forceinline__ void gemm_v_body(const float* __restrict__ A,
                                            const float* __restrict__ B,
                                            unsigned short* __restrict__ C,
                                            int M, int N, int K,
                                            int bx, int by) {
    __shared__ unsigned short Asv[64][72];
    __shared__ unsigned short Bsv[64][72];

    const int t  = threadIdx.x;
    const int m0 = by * 64;
    const int n0 = bx * 64;
    const int rl = t >> 2;
    const int c4 = (t & 3) * 16;

    const int lane = t & 63, w = t >> 6, lr = lane & 15, quad = lane >> 4;

    f32x4 acc[4] = {{0.f,0.f,0.f,0.f},{0.f,0.f,0.f,0.f},
                    {0.f,0.f,0.f,0.f},{0.f,0.f,0.f,0.f}};

    float4 fa[4], fb[4];
    auto LDA = [&](int k0) {
        const float* p = &A[(size_t)(m0 + rl) * K + k0 + c4];
        fa[0] = *(const float4*)&p[0];  fa[1] = *(const float4*)&p[4];
        fa[2] = *(const float4*)&p[8];  fa[3] = *(const float4*)&p[12];
    };
    auto LDB = [&](int k0) {
        const float* p = &B[(size_t)(k0 + rl) * N + n0 + c4];
        fb[0] = *(const float4*)&p[0];  fb[1] = *(const float4*)&p[4];
        fb[2] = *(const float4*)&p[8];  fb[3] = *(const float4*)&p[12];
    };

    LDA(0); LDB(0);
    for (int k0 = 0; k0 < K; k0 += 64) {
        __syncthreads();
        *(bf16x8*)&Asv[rl][c4]     = pack8(fa[0], fa[1]);
        *(bf16x8*)&Asv[rl][c4 + 8] = pack8(fa[2], fa[3]);
        #pragma unroll
        for (int f = 0; f < 4; ++f) {   // B transpose: Bsv[n][k]
            float4 v = fb[f];
            Bsv[c4 + f*4 + 0][rl] = f2b(v.x);
            Bsv[c4 + f*4 + 1][rl] = f2b(v.y);
            Bsv[c4 + f*4 + 2][rl] = f2b(v.z);
            Bsv[c4 + f*4 + 3][rl] = f2b(v.w);
        }
        __syncthreads();

        if (k0 + 64 < K) { LDA(k0 + 64); LDB(k0 + 64); }

        bf16x8 a0 = *(const bf16x8*)&Asv[w * 16 + lr][quad * 8];
        bf16x8 a1 = *(const bf16x8*)&Asv[w * 16 + lr][32 + quad * 8];
        #pragma unroll
        for (int nt = 0; nt < 4; ++nt) {
            bf16x8 b0 = *(const bf16x8*)&Bsv[nt * 16 + lr][quad * 8];
            bf16x8 b1 = *(const bf16x8*)&Bsv[nt * 16 + lr][32 + quad * 8];
            acc[nt] = __builtin_amdgcn_mfma_f32_16x16x32_bf16(a0, b0, acc[nt], 0, 0, 0);
            acc[nt] = __builtin_amdgcn_mfma_f32_16x16x32_bf16(a1, b1, acc[nt], 0, 0, 0);
        }
    }

    #pragma unroll
    for (int nt = 0; nt < 4; ++nt)
        #pragma unroll
        for (int r = 0; r < 4; ++r) {
            int m = m0 + w * 16 + quad * 4 + r;
            int n = n0 + nt * 16 + lr;
            C[(size_t)m * N + n] = f2b(acc[nt][r]);
        }
}

// ---------------------------------------------------------------------------
// V projection (bf16 MFMA) with chunk_keys FUSED as an extra block-row
// (by==32): K is complete when this dispatch runs (stream-ordered after
// gemm_qk2). Block (0,32) also zeroes the routing counters.
// ---------------------------------------------------------------------------
__global__ __launch_bounds__(256) void gemm_v_ck(const float* __restrict__ x,
                                                 const float* __restrict__ Wv,
                                                 unsigned short* __restrict__ Vbf,
                                                 const float* __restrict__ K,
                                                 float* __restrict__ ck,
                                                 int* __restrict__ cur) {
    if (blockIdx.y == 32) {
        int t = threadIdx.x;
        if (blockIdx.x == 0) cur[t] = 0;
        for (int i = blockIdx.x * 256 + t; i < C_NUM * D_DIM; i += 8 * 256) {
            int c = i >> 9;
            int d = i & 511;
            const float* p = K + (size_t)c * 64 * D_DIM + d;
            float sum = 0.f;
            #pragma unroll
            for (int r = 0; r < 64; ++r) sum += p[(size_t)r * D_DIM];
            ck[(size_t)c * D_DIM + d] = sum * (1.0f / 64.0f);
        }
        return;
    }
    gemm_v_body(x, Wv, Vbf, S_LEN, D_DIM, D_DIM, blockIdx.x, blockIdx.y);
}

// ---------------------------------------------------------------------------
// Fused sims + top-5 + scatter (fp32, unchanged — routing-faithful).
// ---------------------------------------------------------------------------
__global__ __launch_bounds__(256) void sims_topk(const float* __restrict__ Q,
                                                 const float* __restrict__ ck,
                                                 int* __restrict__ cur,
                                                 unsigned short* __restrict__ qlist) {
    __shared__ float qtile[64][68];
    __shared__ float cks[32][68];
    __shared__ float simsb[64][36];
    __shared__ int   lds_cnt[32];
    __shared__ int   lds_base[32];

    const int t  = threadIdx.x;
    const int s0 = blockIdx.x * 64;
    const int h  = blockIdx.y;

    if (t < 32) lds_cnt[t] = 0;

    {
        int r = t >> 2;
        #pragma unroll
        for (int i = 0; i < 4; ++i) {
            int cf4 = (t & 3) * 4 + i;
            *(float4*)&qtile[r][cf4 * 4] =
                *(const float4*)&Q[(size_t)(s0 + r) * D_DIM + h * HD + cf4 * 4];
        }
    }
    for (int i = t; i < C_NUM * 16; i += 256) {
        int c = i >> 4, df4 = i & 15;
        *(float4*)&cks[c][df4 * 4] =
            *(const float4*)&ck[(size_t)c * D_DIM + h * HD + df4 * 4];
    }
    __syncthreads();

    {
        const int sl = t >> 2, g = t & 3;
        float sa[8] = {0.f,0.f,0.f,0.f,0.f,0.f,0.f,0.f};
        #pragma unroll
        for (int d4 = 0; d4 < 16; ++d4) {
            float4 q4 = *(const float4*)&qtile[sl][d4 * 4];
            #pragma unroll
            for (int j = 0; j < 8; ++j) {
                float4 c4 = *(const float4*)&cks[g * 8 + j][d4 * 4];
                sa[j] += q4.x*c4.x + q4.y*c4.y + q4.z*c4.z + q4.w*c4.w;
            }
        }
        *(float4*)&simsb[sl][g*8 + 0] = make_float4(sa[0], sa[1], sa[2], sa[3]);
        *(float4*)&simsb[sl][g*8 + 4] = make_float4(sa[4], sa[5], sa[6], sa[7]);
    }
    __syncthreads();

    int csel[TOPK], lpos[TOPK];
    if (t < 64) {
        float sv[32];
        #pragma unroll
        for (int cq = 0; cq < 8; ++cq) {
            float4 v = *(const float4*)&simsb[t][cq * 4];
            sv[cq*4+0] = v.x; sv[cq*4+1] = v.y; sv[cq*4+2] = v.z; sv[cq*4+3] = v.w;
        }
        #pragma unroll
        for (int k = 0; k < TOPK; ++k) {
            float best = -INFINITY; int bi = 0;
            #pragma unroll
            for (int cc = 0; cc < 32; ++cc) {
                bool gt = sv[cc] > best;
                best = gt ? sv[cc] : best;
                bi   = gt ? cc : bi;
            }
            #pragma unroll
            for (int cc = 0; cc < 32; ++cc)
                if (cc == bi) sv[cc] = -INFINITY;
            csel[k] = bi;
            lpos[k] = atomicAdd(&lds_cnt[bi], 1);
        }
    }
    __syncthreads();

    if (t < 32) lds_base[t] = atomicAdd(&cur[h * 32 + t], lds_cnt[t]);
    __syncthreads();

    if (t < 64) {
        #pragma unroll
        for (int k = 0; k < TOPK; ++k) {
            int c = csel[k];
            int pos = lds_base[c] + lpos[k];
            if (pos < QCAP)
                qlist[(size_t)(h * 32 + c) * QCAP + pos] =
                    (unsigned short)((s0 + t) | (k << 11));
        }
    }
}

// ---------------------------------------------------------------------------
// MFMA chunk-centric attention (v6 — unchanged from round 12).
// ---------------------------------------------------------------------------
__global__ __launch_bounds__(256) void moc_attn6(const float* __restrict__ Q,
                                                 const float* __restrict__ K,
                                                 const unsigned short* __restrict__ Vbf,
                                                 const int* __restrict__ cnt,
                                                 const unsigned short* __restrict__ qlist,
                                                 float* __restrict__ lpart,
                                                 float* __restrict__ Opart) {
    __shared__ unsigned short Qs[64][72];
    __shared__ unsigned short Ks[64][72];
    __shared__ unsigned short VT[64][72];
    __shared__ unsigned short Ps[64][72];
    __shared__ unsigned short slist[64];

    const int hc = blockIdx.y;
    const int h  = hc >> 5;
    const int c  = hc & 31;
    const int g  = blockIdx.x;
    const int t  = threadIdx.x;

    const int count = min(cnt[hc], QCAP);
    const int base  = g * 64;
    if (base >= count) return;
    const int lim = min(count - base, 64);

    const float* Kb = K + ((size_t)c * 64) * D_DIM + h * HD;
    const unsigned short* Vb = Vbf + ((size_t)c * 64) * D_DIM + h * HD;
    const unsigned short* list = qlist + (size_t)hc * QCAP + base;

    {
        const int j  = t >> 2;
        const int d0 = (t & 3) * 16;

        const float* kr = Kb + (size_t)j * D_DIM + d0;
        float4 k0 = *(const float4*)&kr[0],  k1 = *(const float4*)&kr[4];
        float4 k2 = *(const float4*)&kr[8],  k3 = *(const float4*)&kr[12];
        *(bf16x8*)&Ks[j][d0]     = pack8(k0, k1);
        *(bf16x8*)&Ks[j][d0 + 8] = pack8(k2, k3);

        const unsigned short* vr = Vb + (size_t)j * D_DIM + d0;
        bf16x8 v0 = *(const bf16x8*)&vr[0];
        bf16x8 v1 = *(const bf16x8*)&vr[8];
        #pragma unroll
        for (int i = 0; i < 8; ++i) {
            VT[d0 + i][j]     = (unsigned short)v0[i];
            VT[d0 + 8 + i][j] = (unsigned short)v1[i];
        }

        unsigned short pv = (j < lim) ? list[j] : (unsigned short)0xFFFF;
        if ((t & 3) == 0) slist[j] = pv;
        int s = (pv == 0xFFFF) ? 0 : (int)(pv & 2047);
        const float* qr = Q + (size_t)s * D_DIM + h * HD + d0;
        float4 q0 = *(const float4*)&qr[0],  q1 = *(const float4*)&qr[4];
        float4 q2 = *(const float4*)&qr[8],  q3 = *(const float4*)&qr[12];
        *(bf16x8*)&Qs[j][d0]     = pack8(q0, q1);
        *(bf16x8*)&Qs[j][d0 + 8] = pack8(q2, q3);
    }
    __syncthreads();

    const int lane = t & 63;
    const int w    = t >> 6;
    const int lr   = lane & 15;
    const int quad = lane >> 4;

    bf16x8 aq0 = *(const bf16x8*)&Qs[w * 16 + lr][quad * 8];
    bf16x8 aq1 = *(const bf16x8*)&Qs[w * 16 + lr][32 + quad * 8];

    f32x4 acc[4];
    #pragma unroll
    for (int kt = 0; kt < 4; ++kt) {
        bf16x8 b0 = *(const bf16x8*)&Ks[kt * 16 + lr][quad * 8];
        bf16x8 b1 = *(const bf16x8*)&Ks[kt * 16 + lr][32 + quad * 8];
        f32x4 z = {0.f, 0.f, 0.f, 0.f};
        z = __builtin_amdgcn_mfma_f32_16x16x32_bf16(aq0, b0, z, 0, 0, 0);
        z = __builtin_amdgcn_mfma_f32_16x16x32_bf16(aq1, b1, z, 0, 0, 0);
        acc[kt] = z;
    }

    unsigned short pb[4][4];
    float dsum[4] = {0.f, 0.f, 0.f, 0.f};
    #pragma unroll
    for (int kt = 0; kt < 4; ++kt) {
        #pragma unroll
        for (int r = 0; r < 4; ++r) {
            unsigned short u = f2b(__expf(acc[kt][r] * SCALE));
            pb[kt][r] = u;
            dsum[r] += b2f(u);
        }
    }
    #pragma unroll
    for (int r = 0; r < 4; ++r) {
        float v = dsum[r];
        v += __shfl_xor(v, 1, 64);
        v += __shfl_xor(v, 2, 64);
        v += __shfl_xor(v, 4, 64);
        v += __shfl_xor(v, 8, 64);
        dsum[r] = v;
    }
    if (lr == 0) {
        #pragma unroll
        for (int r = 0; r < 4; ++r) {
            unsigned short sv = slist[w * 16 + quad * 4 + r];
            if (sv != 0xFFFF) {
                int kk = sv >> 11, s = sv & 2047;
                lpart[((size_t)kk * H_NUM + h) * S_LEN + s] = dsum[r];
            }
        }
    }

    #pragma unroll
    for (int kt = 0; kt < 4; ++kt)
        #pragma unroll
        for (int r = 0; r < 4; ++r)
            Ps[w * 16 + quad * 4 + r][kt * 16 + lr] = pb[kt][r];

    bf16x8 ap0 = *(const bf16x8*)&Ps[w * 16 + lr][quad * 8];
    bf16x8 ap1 = *(const bf16x8*)&Ps[w * 16 + lr][32 + quad * 8];

    #pragma unroll
    for (int dt = 0; dt < 4; ++dt) {
        bf16x8 b0 = *(const bf16x8*)&VT[dt * 16 + lr][quad * 8];
        bf16x8 b1 = *(const bf16x8*)&VT[dt * 16 + lr][32 + quad * 8];
        f32x4 z = {0.f, 0.f, 0.f, 0.f};
        z = __builtin_amdgcn_mfma_f32_16x16x32_bf16(ap0, b0, z, 0, 0, 0);
        z = __builtin_amdgcn_mfma_f32_16x16x32_bf16(ap1, b1, z, 0, 0, 0);
        #pragma unroll
        for (int r = 0; r < 4; ++r) {
            unsigned short sv = slist[w * 16 + quad * 4 + r];
            if (sv != 0xFFFF) {
                int kk = sv >> 11, s = sv & 2047;
                Opart[((((size_t)kk * H_NUM + h) * S_LEN + s) * HD) + dt * 16 + lr] = z[r];
            }
        }
    }
}

// ---------------------------------------------------------------------------
// Obn_bf[s][h*64+d] = bf16( (sum_k Opart[k][h][s][d]) / (sum_k lpart) )
// (one-pass reduce; R13's fusion into gemm_out re-read Opart 8x — reverted)
// ---------------------------------------------------------------------------
__global__ __launch_bounds__(256) void reduce_norm(const float4* __restrict__ Opart4,
                                                   const float* __restrict__ lpart,
                                                   unsigned short* __restrict__ Obn) {
    int i = blockIdx.x * 256 + threadIdx.x;
    int s    = i >> 7;
    int col4 = i & 127;
    int h    = col4 >> 4;
    int f4   = col4 & 15;
    float4 acc = make_float4(0.f,0.f,0.f,0.f);
    float  den = 0.f;
    #pragma unroll
    for (int k = 0; k < TOPK; ++k) {
        size_t slot = ((size_t)k * H_NUM + h) * S_LEN + s;
        float4 v = Opart4[slot * 16 + f4];
        acc.x += v.x; acc.y += v.y; acc.z += v.z; acc.w += v.w;
        den += lpart[slot];
    }
    float inv = 1.0f / den;
    us4 o;
    o[0] = f2b(acc.x * inv); o[1] = f2b(acc.y * inv);
    o[2] = f2b(acc.z * inv); o[3] = f2b(acc.w * inv);
    *(us4*)&Obn[(size_t)i * 4] = o;
}

// ---------------------------------------------------------------------------
// Output projection: bf16 A (normalized attention out), fp32 C (MFMA).
// ---------------------------------------------------------------------------
__global__ __launch_bounds__(256) void gemm_out(const unsigned short* __restrict__ Obn,
                                                const float* __restrict__ Wo,
                                                float* __restrict__ out) {
    __shared__ unsigned short As[64][72];
    __shared__ unsigned short Bs[64][72];

    const int t  = threadIdx.x;
    const int m0 = blockIdx.y * 64;
    const int n0 = blockIdx.x * 64;
    const int rl = t >> 2;
    const int c4 = (t & 3) * 16;
    const int N = D_DIM, K = D_DIM;

    const int lane = t & 63, w = t >> 6, lr = lane & 15, quad = lane >> 4;

    f32x4 acc[4] = {{0.f,0.f,0.f,0.f},{0.f,0.f,0.f,0.f},
                    {0.f,0.f,0.f,0.f},{0.f,0.f,0.f,0.f}};

    bf16x8 ba[2]; float4 fb[4];
    auto LDA = [&](int k0) {
        const unsigned short* p = &Obn[(size_t)(m0 + rl) * K + k0 + c4];
        ba[0] = *(const bf16x8*)&p[0];
        ba[1] = *(const bf16x8*)&p[8];
    };
    auto LDB = [&](int k0) {
        const float* p = &Wo[(size_t)(k0 + rl) * N + n0 + c4];
        fb[0] = *(const float4*)&p[0];  fb[1] = *(const float4*)&p[4];
        fb[2] = *(const float4*)&p[8];  fb[3] = *(const float4*)&p[12];
    };

    LDA(0); LDB(0);
    for (int k0 = 0; k0 < K; k0 += 64) {
        __syncthreads();
        *(bf16x8*)&As[rl][c4]     = ba[0];
        *(bf16x8*)&As[rl][c4 + 8] = ba[1];
        #pragma unroll
        for (int f = 0; f < 4; ++f) {
            float4 v = fb[f];
            Bs[c4 + f*4 + 0][rl] = f2b(v.x);
            Bs[c4 + f*4 + 1][rl] = f2b(v.y);
            Bs[c4 + f*4 + 2][rl] = f2b(v.z);
            Bs[c4 + f*4 + 3][rl] = f2b(v.w);
        }
        __syncthreads();

        if (k0 + 64 < K) { LDA(k0 + 64); LDB(k0 + 64); }

        bf16x8 a0 = *(const bf16x8*)&As[w * 16 + lr][quad * 8];
        bf16x8 a1 = *(const bf16x8*)&As[w * 16 + lr][32 + quad * 8];
        #pragma unroll
        for (int nt = 0; nt < 4; ++nt) {
            bf16x8 b0 = *(const bf16x8*)&Bs[nt * 16 + lr][quad * 8];
            bf16x8 b1 = *(const bf16x8*)&Bs[nt * 16 + lr][32 + quad * 8];
            acc[nt] = __builtin_amdgcn_mfma_f32_16x16x32_bf16(a0, b0, acc[nt], 0, 0, 0);
            acc[nt] = __builtin_amdgcn_mfma_f32_16x16x32_bf16(a1, b1, acc[nt], 0, 0, 0);
        }
    }

    #pragma unroll
    for (int nt = 0; nt < 4; ++nt)
        #pragma unroll
        for (int r = 0; r < 4; ++r) {
            int m = m0 + w * 16 + quad * 4 + r;
            int n = n0 + nt * 16 + lr;
            out[(size_t)m * N + n] = acc[nt][r];
        }
}

// ---------------------------------------------------------------------------
// Workspace: Qb 4MB (reused as Obn bf16 2MB) | Kb 4MB | Vbf ushort 2MB
//   | ck 64KB | lpart 320KB | cur 1KB | qlist 512KB | Opart 20MB  ≈ 31 MB
// ---------------------------------------------------------------------------
extern "C" void kernel_launch(void* const* d_in, const int* in_sizes, int n_in,
                              void* d_out, int out_size, void* d_ws, size_t ws_size,
                              hipStream_t stream) {
    const float* x  = (const float*)d_in[0];
    const float* Wq = (const float*)d_in[1];
    const float* Wk = (const float*)d_in[2];
    const float* Wv = (const float*)d_in[3];
    const float* Wo = (const float*)d_in[4];
    float* out = (float*)d_out;

    const size_t SD = (size_t)S_LEN * D_DIM;
    float* ws    = (float*)d_ws;
    float* Qb    = ws;                                    // later: Obn (bf16)
    float* Kb    = Qb + SD;
    unsigned short* Vbf = (unsigned short*)(Kb + SD);     // [2048][512] bf16
    float* ck    = (float*)(Vbf + SD);
    float* lpart = ck + (size_t)C_NUM * D_DIM;
    int*   curb  = (int*)(lpart + (size_t)TOPK * H_NUM * S_LEN);
    unsigned short* qlst = (unsigned short*)(curb + 256);
    float* Opart = (float*)(qlst + (size_t)256 * QCAP);
    unsigned short* Obn = (unsigned short*)Qb;

    dim3 qkgrid(D_DIM / BN, S_LEN / BM);         // (8, 32): dual-output Q+K
    gemm_qk2<<<qkgrid, 256, 0, stream>>>(x, Wq, Wk, Qb, Kb);

    dim3 vgrid(D_DIM / 64, S_LEN / 64 + 1);      // (8, 33): V MFMA + chunk_keys + cur
    gemm_v_ck<<<vgrid, 256, 0, stream>>>(x, Wv, Vbf, Kb, ck, curb);

    dim3 rgrid(S_LEN / 64, H_NUM);
    sims_topk<<<rgrid, 256, 0, stream>>>(Qb, ck, curb, qlst);

    dim3 agrid(ATILES, H_NUM * C_NUM);
    moc_attn6<<<agrid, 256, 0, stream>>>(Qb, Kb, Vbf, curb, qlst, lpart, Opart);

    reduce_norm<<<(int)(SD / 4 / 256), 256, 0, stream>>>((const float4*)Opart, lpart, Obn);

    dim3 ogrid(D_DIM / 64, S_LEN / 64);
    gemm_out<<<ogrid, 256, 0, stream>>>(Obn, Wo, out);
}

// Round 15
// 181.803 us; speedup vs baseline: 1.1522x; 1.1522x over previous
//
#include <hip/hip_runtime.h>
#include <hip/hip_bf16.h>
#include <math.h>

// Problem constants (B=1)
#define S_LEN 2048
#define D_DIM 512
#define H_NUM 8
#define HD    64
#define C_NUM 32
#define TOPK  5
#define SCALE 0.125f   // hd^-0.5
#define QCAP  1024     // fixed qlist capacity per (h,c); load is ~320
#define ATILES 16      // query tiles per (h,c); empties exit fast

typedef __attribute__((ext_vector_type(8))) short bf16x8;   // 8 bf16 (4 VGPRs)
typedef __attribute__((ext_vector_type(4))) float f32x4;
typedef __attribute__((ext_vector_type(4))) unsigned short us4;

__device__ __forceinline__ unsigned short f2b(float f) {
    __hip_bfloat16 h = __float2bfloat16(f);
    unsigned short u;
    __builtin_memcpy(&u, &h, 2);
    return u;
}
__device__ __forceinline__ bf16x8 pack8(float4 a, float4 b) {
    bf16x8 r;
    r[0] = (short)f2b(a.x); r[1] = (short)f2b(a.y);
    r[2] = (short)f2b(a.z); r[3] = (short)f2b(a.w);
    r[4] = (short)f2b(b.x); r[5] = (short)f2b(b.y);
    r[6] = (short)f2b(b.z); r[7] = (short)f2b(b.w);
    return r;
}
__device__ __forceinline__ float b2f(unsigned short u) {
    __hip_bfloat16 h;
    __builtin_memcpy(&h, &u, 2);
    return __bfloat162float(h);
}

// ---------------------------------------------------------------------------
// fp32 GEMM body (R12-proven). Now used ONLY for the small sims GEMM
// (M=2048, N=256, K=512) — the routing-critical fp32 path.
// ---------------------------------------------------------------------------
#define BM 64
#define BN 64
#define BK 32

__device__ __forceinline__ void gemm_body(const float* __restrict__ A,
                                          const float* __restrict__ B,
                                          float* __restrict__ C,
                                          int M, int N, int K,
                                          int bx, int by) {
    __shared__ float As[BK][BM + 4];
    __shared__ float Bs[BK][BN];

    const int t  = threadIdx.x;
    const int tx = t & 15;
    const int ty = t >> 4;
    const int m0 = by * BM;
    const int n0 = bx * BN;

    float4 acc0 = make_float4(0.f,0.f,0.f,0.f);
    float4 acc1 = make_float4(0.f,0.f,0.f,0.f);
    float4 acc2 = make_float4(0.f,0.f,0.f,0.f);
    float4 acc3 = make_float4(0.f,0.f,0.f,0.f);

    const int ar = t >> 3;
    const int ac = (t & 7) * 4;
    const int br = t >> 4;
    const int bc = (t & 15) * 4;

    float4 a0, a1, b0, b1;
    auto LD = [&](int k0) {
        a0 = *(const float4*)&A[(size_t)(m0 + ar)      * K + k0 + ac];
        a1 = *(const float4*)&A[(size_t)(m0 + ar + 32) * K + k0 + ac];
        b0 = *(const float4*)&B[(size_t)(k0 + br)      * N + n0 + bc];
        b1 = *(const float4*)&B[(size_t)(k0 + br + 16) * N + n0 + bc];
    };

    LD(0);
    for (int k0 = 0; k0 < K; k0 += BK) {
        __syncthreads();
        As[ac+0][ar]    = a0.x; As[ac+1][ar]    = a0.y; As[ac+2][ar]    = a0.z; As[ac+3][ar]    = a0.w;
        As[ac+0][ar+32] = a1.x; As[ac+1][ar+32] = a1.y; As[ac+2][ar+32] = a1.z; As[ac+3][ar+32] = a1.w;
        *(float4*)&Bs[br][bc]      = b0;
        *(float4*)&Bs[br + 16][bc] = b1;
        __syncthreads();

        if (k0 + BK < K) LD(k0 + BK);

        #pragma unroll
        for (int kk = 0; kk < BK; ++kk) {
            float4 a = *(const float4*)&As[kk][ty * 4];
            float4 b = *(const float4*)&Bs[kk][tx * 4];
            acc0.x += a.x*b.x; acc0.y += a.x*b.y; acc0.z += a.x*b.z; acc0.w += a.x*b.w;
            acc1.x += a.y*b.x; acc1.y += a.y*b.y; acc1.z += a.y*b.z; acc1.w += a.y*b.w;
            acc2.x += a.z*b.x; acc2.y += a.z*b.y; acc2.z += a.z*b.z; acc2.w += a.z*b.w;
            acc3.x += a.w*b.x; acc3.y += a.w*b.y; acc3.z += a.w*b.z; acc3.w += a.w*b.w;
        }
    }

    *(float4*)&C[(size_t)(m0 + ty*4 + 0) * N + n0 + tx*4] = acc0;
    *(float4*)&C[(size_t)(m0 + ty*4 + 1) * N + n0 + tx*4] = acc1;
    *(float4*)&C[(size_t)(m0 + ty*4 + 2) * N + n0 + tx*4] = acc2;
    *(float4*)&C[(size_t)(m0 + ty*4 + 3) * N + n0 + tx*4] = acc3;
}

__global__ __launch_bounds__(256) void sims_gemm(const float* __restrict__ x,
                                                 const float* __restrict__ G,
                                                 float* __restrict__ sims) {
    gemm_body(x, G, sims, S_LEN, H_NUM * C_NUM, D_DIM, blockIdx.x, blockIdx.y);
}

// ---------------------------------------------------------------------------
// bf16 MFMA GEMM body (fp32 A, fp32 B, bf16 C). R11/R12-proven layouts.
// ---------------------------------------------------------------------------
__device__ __forceinline__ void gemm_v_body(const float* __restrict__ A,
                                            const float* __restrict__ B,
                                            unsigned short* __restrict__ C,
                                            int M, int N, int K,
                                            int bx, int by) {
    __shared__ unsigned short Asv[64][72];
    __shared__ unsigned short Bsv[64][72];

    const int t  = threadIdx.x;
    const int m0 = by * 64;
    const int n0 = bx * 64;
    const int rl = t >> 2;
    const int c4 = (t & 3) * 16;

    const int lane = t & 63, w = t >> 6, lr = lane & 15, quad = lane >> 4;

    f32x4 acc[4] = {{0.f,0.f,0.f,0.f},{0.f,0.f,0.f,0.f},
                    {0.f,0.f,0.f,0.f},{0.f,0.f,0.f,0.f}};

    float4 fa[4], fb[4];
    auto LDA = [&](int k0) {
        const float* p = &A[(size_t)(m0 + rl) * K + k0 + c4];
        fa[0] = *(const float4*)&p[0];  fa[1] = *(const float4*)&p[4];
        fa[2] = *(const float4*)&p[8];  fa[3] = *(const float4*)&p[12];
    };
    auto LDB = [&](int k0) {
        const float* p = &B[(size_t)(k0 + rl) * N + n0 + c4];
        fb[0] = *(const float4*)&p[0];  fb[1] = *(const float4*)&p[4];
        fb[2] = *(const float4*)&p[8];  fb[3] = *(const float4*)&p[12];
    };

    LDA(0); LDB(0);
    for (int k0 = 0; k0 < K; k0 += 64) {
        __syncthreads();
        *(bf16x8*)&Asv[rl][c4]     = pack8(fa[0], fa[1]);
        *(bf16x8*)&Asv[rl][c4 + 8] = pack8(fa[2], fa[3]);
        #pragma unroll
        for (int f = 0; f < 4; ++f) {   // B transpose: Bsv[n][k]
            float4 v = fb[f];
            Bsv[c4 + f*4 + 0][rl] = f2b(v.x);
            Bsv[c4 + f*4 + 1][rl] = f2b(v.y);
            Bsv[c4 + f*4 + 2][rl] = f2b(v.z);
            Bsv[c4 + f*4 + 3][rl] = f2b(v.w);
        }
        __syncthreads();

        if (k0 + 64 < K) { LDA(k0 + 64); LDB(k0 + 64); }

        bf16x8 a0 = *(const bf16x8*)&Asv[w * 16 + lr][quad * 8];
        bf16x8 a1 = *(const bf16x8*)&Asv[w * 16 + lr][32 + quad * 8];
        #pragma unroll
        for (int nt = 0; nt < 4; ++nt) {
            bf16x8 b0 = *(const bf16x8*)&Bsv[nt * 16 + lr][quad * 8];
            bf16x8 b1 = *(const bf16x8*)&Bsv[nt * 16 + lr][32 + quad * 8];
            acc[nt] = __builtin_amdgcn_mfma_f32_16x16x32_bf16(a0, b0, acc[nt], 0, 0, 0);
            acc[nt] = __builtin_amdgcn_mfma_f32_16x16x32_bf16(a1, b1, acc[nt], 0, 0, 0);
        }
    }

    #pragma unroll
    for (int nt = 0; nt < 4; ++nt)
        #pragma unroll
        for (int r = 0; r < 4; ++r) {
            int m = m0 + w * 16 + quad * 4 + r;
            int n = n0 + nt * 16 + lr;
            C[(size_t)m * N + n] = f2b(acc[nt][r]);
        }
}

// ---------------------------------------------------------------------------
// All projections in one dispatch: z=0/1/2 -> Q/K/V bf16 MFMA GEMMs (Q,K now
// feed ONLY attention, which is bf16 anyway — routing no longer needs them).
// z=3: xbar (per-chunk mean of x, fp32; one 64-load sum per thread — the
// R12-proven shape) + routing-counter zeroing.
// ---------------------------------------------------------------------------
__global__ __launch_bounds__(256) void proj_all(const float* __restrict__ x,
                                                const float* __restrict__ Wq,
                                                const float* __restrict__ Wk,
                                                const float* __restrict__ Wv,
                                                unsigned short* __restrict__ Qbf,
                                                unsigned short* __restrict__ Kbf,
                                                unsigned short* __restrict__ Vbf,
                                                float* __restrict__ xbar,
                                                int* __restrict__ cur) {
    if (blockIdx.z == 3) {
        int t = threadIdx.x;
        if (blockIdx.x == 0 && blockIdx.y == 0) cur[t] = 0;
        int flat = (blockIdx.y * 8 + blockIdx.x) * 256 + t;
        if (flat < C_NUM * D_DIM) {
            int c = flat >> 9, d = flat & 511;
            const float* p = x + (size_t)c * 64 * D_DIM + d;
            float s = 0.f;
            #pragma unroll
            for (int r = 0; r < 64; ++r) s += p[(size_t)r * D_DIM];
            xbar[flat] = s * (1.0f / 64.0f);
        }
        return;
    }
    const float* W = (blockIdx.z == 0) ? Wq : (blockIdx.z == 1) ? Wk : Wv;
    unsigned short* C = (blockIdx.z == 0) ? Qbf : (blockIdx.z == 1) ? Kbf : Vbf;
    gemm_v_body(x, W, C, S_LEN, D_DIM, D_DIM, blockIdx.x, blockIdx.y);
}

// ---------------------------------------------------------------------------
// ck[c][:] = xbar[c] @ Wk   (fp32; 32 blocks, thread t -> cols t, t+256)
// ---------------------------------------------------------------------------
__global__ __launch_bounds__(256) void ck_kernel(const float* __restrict__ xbar,
                                                 const float* __restrict__ Wk,
                                                 float* __restrict__ ck) {
    __shared__ float xl[512];
    const int c = blockIdx.x, t = threadIdx.x;
    xl[t]       = xbar[c * 512 + t];
    xl[t + 256] = xbar[c * 512 + t + 256];
    __syncthreads();
    float s0 = 0.f, s1 = 0.f;
    #pragma unroll 8
    for (int j = 0; j < 512; ++j) {
        float xv = xl[j];
        s0 += xv * Wk[(size_t)j * 512 + t];
        s1 += xv * Wk[(size_t)j * 512 + t + 256];
    }
    ck[c * 512 + t]       = s0;
    ck[c * 512 + t + 256] = s1;
}

// ---------------------------------------------------------------------------
// G[j][(h,c)] = sum_d Wq[j][h*64+d] * ck[c][h*64+d]   (fp32; 512 blocks)
// sims = x @ G then equals Q . ck per head (reassociated — fp32 throughout).
// ---------------------------------------------------------------------------
__global__ __launch_bounds__(256) void g_kernel(const float* __restrict__ Wq,
                                                const float* __restrict__ ck,
                                                float* __restrict__ G) {
    __shared__ float ckl[32][513];
    __shared__ float wql[512];
    const int j = blockIdx.x, t = threadIdx.x;
    for (int i = t; i < 32 * 512; i += 256) ckl[i >> 9][i & 511] = ck[i];
    wql[t]       = Wq[(size_t)j * 512 + t];
    wql[t + 256] = Wq[(size_t)j * 512 + t + 256];
    __syncthreads();
    const int h = t >> 5, c = t & 31;
    float s = 0.f;
    #pragma unroll
    for (int d = 0; d < 64; ++d) s += wql[h * 64 + d] * ckl[c][h * 64 + d];
    G[(size_t)j * 256 + t] = s;
}

// ---------------------------------------------------------------------------
// Top-5 + scatter from precomputed sims (tie-break: strict > over ascending c
// == jax top_k). qlist packs rank k (bits 11..13) with query id (bits 0..10).
// ---------------------------------------------------------------------------
__global__ __launch_bounds__(256) void topk_scatter(const float* __restrict__ sims,
                                                    int* __restrict__ cur,
                                                    unsigned short* __restrict__ qlist) {
    __shared__ float simsb[64][36];
    __shared__ int   lds_cnt[32];
    __shared__ int   lds_base[32];

    const int t  = threadIdx.x;
    const int s0 = blockIdx.x * 64;
    const int h  = blockIdx.y;

    if (t < 32) lds_cnt[t] = 0;
    {
        int r = t >> 2, cg = (t & 3) * 8;
        const float* sp = sims + (size_t)(s0 + r) * 256 + h * 32 + cg;
        *(float4*)&simsb[r][cg]     = *(const float4*)&sp[0];
        *(float4*)&simsb[r][cg + 4] = *(const float4*)&sp[4];
    }
    __syncthreads();

    int csel[TOPK], lpos[TOPK];
    if (t < 64) {
        float sv[32];
        #pragma unroll
        for (int cq = 0; cq < 8; ++cq) {
            float4 v = *(const float4*)&simsb[t][cq * 4];
            sv[cq*4+0] = v.x; sv[cq*4+1] = v.y; sv[cq*4+2] = v.z; sv[cq*4+3] = v.w;
        }
        #pragma unroll
        for (int k = 0; k < TOPK; ++k) {
            float best = -INFINITY; int bi = 0;
            #pragma unroll
            for (int cc = 0; cc < 32; ++cc) {
                bool gt = sv[cc] > best;
                best = gt ? sv[cc] : best;
                bi   = gt ? cc : bi;
            }
            #pragma unroll
            for (int cc = 0; cc < 32; ++cc)
                if (cc == bi) sv[cc] = -INFINITY;
            csel[k] = bi;
            lpos[k] = atomicAdd(&lds_cnt[bi], 1);
        }
    }
    __syncthreads();

    if (t < 32) lds_base[t] = atomicAdd(&cur[h * 32 + t], lds_cnt[t]);
    __syncthreads();

    if (t < 64) {
        #pragma unroll
        for (int k = 0; k < TOPK; ++k) {
            int c = csel[k];
            int pos = lds_base[c] + lpos[k];
            if (pos < QCAP)
                qlist[(size_t)(h * 32 + c) * QCAP + pos] =
                    (unsigned short)((s0 + t) | (k << 11));
        }
    }
}

// ---------------------------------------------------------------------------
// MFMA chunk-centric attention (v6b — Q/K/V all bf16 sources now).
// One block barrier; unique-writer Opart/lpart stores (no atomics).
// ---------------------------------------------------------------------------
__global__ __launch_bounds__(256) void moc_attn6b(const unsigned short* __restrict__ Qbf,
                                                  const unsigned short* __restrict__ Kbf,
                                                  const unsigned short* __restrict__ Vbf,
                                                  const int* __restrict__ cnt,
                                                  const unsigned short* __restrict__ qlist,
                                                  float* __restrict__ lpart,
                                                  float* __restrict__ Opart) {
    __shared__ unsigned short Qs[64][72];
    __shared__ unsigned short Ks[64][72];
    __shared__ unsigned short VT[64][72];
    __shared__ unsigned short Ps[64][72];
    __shared__ unsigned short slist[64];

    const int hc = blockIdx.y;
    const int h  = hc >> 5;
    const int c  = hc & 31;
    const int g  = blockIdx.x;
    const int t  = threadIdx.x;

    const int count = min(cnt[hc], QCAP);
    const int base  = g * 64;
    if (base >= count) return;
    const int lim = min(count - base, 64);

    const unsigned short* Kb = Kbf + ((size_t)c * 64) * D_DIM + h * HD;
    const unsigned short* Vb = Vbf + ((size_t)c * 64) * D_DIM + h * HD;
    const unsigned short* list = qlist + (size_t)hc * QCAP + base;

    {
        const int j  = t >> 2;
        const int d0 = (t & 3) * 16;

        const unsigned short* kr = Kb + (size_t)j * D_DIM + d0;
        *(bf16x8*)&Ks[j][d0]     = *(const bf16x8*)&kr[0];
        *(bf16x8*)&Ks[j][d0 + 8] = *(const bf16x8*)&kr[8];

        const unsigned short* vr = Vb + (size_t)j * D_DIM + d0;
        bf16x8 v0 = *(const bf16x8*)&vr[0];
        bf16x8 v1 = *(const bf16x8*)&vr[8];
        #pragma unroll
        for (int i = 0; i < 8; ++i) {
            VT[d0 + i][j]     = (unsigned short)v0[i];
            VT[d0 + 8 + i][j] = (unsigned short)v1[i];
        }

        unsigned short pv = (j < lim) ? list[j] : (unsigned short)0xFFFF;
        if ((t & 3) == 0) slist[j] = pv;
        int s = (pv == 0xFFFF) ? 0 : (int)(pv & 2047);
        const unsigned short* qr = Qbf + (size_t)s * D_DIM + h * HD + d0;
        *(bf16x8*)&Qs[j][d0]     = *(const bf16x8*)&qr[0];
        *(bf16x8*)&Qs[j][d0 + 8] = *(const bf16x8*)&qr[8];
    }
    __syncthreads();

    const int lane = t & 63;
    const int w    = t >> 6;
    const int lr   = lane & 15;
    const int quad = lane >> 4;

    bf16x8 aq0 = *(const bf16x8*)&Qs[w * 16 + lr][quad * 8];
    bf16x8 aq1 = *(const bf16x8*)&Qs[w * 16 + lr][32 + quad * 8];

    f32x4 acc[4];
    #pragma unroll
    for (int kt = 0; kt < 4; ++kt) {
        bf16x8 b0 = *(const bf16x8*)&Ks[kt * 16 + lr][quad * 8];
        bf16x8 b1 = *(const bf16x8*)&Ks[kt * 16 + lr][32 + quad * 8];
        f32x4 z = {0.f, 0.f, 0.f, 0.f};
        z = __builtin_amdgcn_mfma_f32_16x16x32_bf16(aq0, b0, z, 0, 0, 0);
        z = __builtin_amdgcn_mfma_f32_16x16x32_bf16(aq1, b1, z, 0, 0, 0);
        acc[kt] = z;
    }

    unsigned short pb[4][4];
    float dsum[4] = {0.f, 0.f, 0.f, 0.f};
    #pragma unroll
    for (int kt = 0; kt < 4; ++kt) {
        #pragma unroll
        for (int r = 0; r < 4; ++r) {
            unsigned short u = f2b(__expf(acc[kt][r] * SCALE));
            pb[kt][r] = u;
            dsum[r] += b2f(u);
        }
    }
    #pragma unroll
    for (int r = 0; r < 4; ++r) {
        float v = dsum[r];
        v += __shfl_xor(v, 1, 64);
        v += __shfl_xor(v, 2, 64);
        v += __shfl_xor(v, 4, 64);
        v += __shfl_xor(v, 8, 64);
        dsum[r] = v;
    }
    if (lr == 0) {
        #pragma unroll
        for (int r = 0; r < 4; ++r) {
            unsigned short sv = slist[w * 16 + quad * 4 + r];
            if (sv != 0xFFFF) {
                int kk = sv >> 11, s = sv & 2047;
                lpart[((size_t)kk * H_NUM + h) * S_LEN + s] = dsum[r];
            }
        }
    }

    #pragma unroll
    for (int kt = 0; kt < 4; ++kt)
        #pragma unroll
        for (int r = 0; r < 4; ++r)
            Ps[w * 16 + quad * 4 + r][kt * 16 + lr] = pb[kt][r];

    bf16x8 ap0 = *(const bf16x8*)&Ps[w * 16 + lr][quad * 8];
    bf16x8 ap1 = *(const bf16x8*)&Ps[w * 16 + lr][32 + quad * 8];

    #pragma unroll
    for (int dt = 0; dt < 4; ++dt) {
        bf16x8 b0 = *(const bf16x8*)&VT[dt * 16 + lr][quad * 8];
        bf16x8 b1 = *(const bf16x8*)&VT[dt * 16 + lr][32 + quad * 8];
        f32x4 z = {0.f, 0.f, 0.f, 0.f};
        z = __builtin_amdgcn_mfma_f32_16x16x32_bf16(ap0, b0, z, 0, 0, 0);
        z = __builtin_amdgcn_mfma_f32_16x16x32_bf16(ap1, b1, z, 0, 0, 0);
        #pragma unroll
        for (int r = 0; r < 4; ++r) {
            unsigned short sv = slist[w * 16 + quad * 4 + r];
            if (sv != 0xFFFF) {
                int kk = sv >> 11, s = sv & 2047;
                Opart[((((size_t)kk * H_NUM + h) * S_LEN + s) * HD) + dt * 16 + lr] = z[r];
            }
        }
    }
}

// ---------------------------------------------------------------------------
// Obn_bf[s][h*64+d] = bf16( (sum_k Opart[k][h][s][d]) / (sum_k lpart) )
// ---------------------------------------------------------------------------
__global__ __launch_bounds__(256) void reduce_norm(const float4* __restrict__ Opart4,
                                                   const float* __restrict__ lpart,
                                                   unsigned short* __restrict__ Obn) {
    int i = blockIdx.x * 256 + threadIdx.x;
    int s    = i >> 7;
    int col4 = i & 127;
    int h    = col4 >> 4;
    int f4   = col4 & 15;
    float4 acc = make_float4(0.f,0.f,0.f,0.f);
    float  den = 0.f;
    #pragma unroll
    for (int k = 0; k < TOPK; ++k) {
        size_t slot = ((size_t)k * H_NUM + h) * S_LEN + s;
        float4 v = Opart4[slot * 16 + f4];
        acc.x += v.x; acc.y += v.y; acc.z += v.z; acc.w += v.w;
        den += lpart[slot];
    }
    float inv = 1.0f / den;
    us4 o;
    o[0] = f2b(acc.x * inv); o[1] = f2b(acc.y * inv);
    o[2] = f2b(acc.z * inv); o[3] = f2b(acc.w * inv);
    *(us4*)&Obn[(size_t)i * 4] = o;
}

// ---------------------------------------------------------------------------
// Output projection: bf16 A (normalized attention out), fp32 C (MFMA).
// ---------------------------------------------------------------------------
__global__ __launch_bounds__(256) void gemm_out(const unsigned short* __restrict__ Obn,
                                                const float* __restrict__ Wo,
                                                float* __restrict__ out) {
    __shared__ unsigned short As[64][72];
    __shared__ unsigned short Bs[64][72];

    const int t  = threadIdx.x;
    const int m0 = blockIdx.y * 64;
    const int n0 = blockIdx.x * 64;
    const int rl = t >> 2;
    const int c4 = (t & 3) * 16;
    const int N = D_DIM, K = D_DIM;

    const int lane = t & 63, w = t >> 6, lr = lane & 15, quad = lane >> 4;

    f32x4 acc[4] = {{0.f,0.f,0.f,0.f},{0.f,0.f,0.f,0.f},
                    {0.f,0.f,0.f,0.f},{0.f,0.f,0.f,0.f}};

    bf16x8 ba[2]; float4 fb[4];
    auto LDA = [&](int k0) {
        const unsigned short* p = &Obn[(size_t)(m0 + rl) * K + k0 + c4];
        ba[0] = *(const bf16x8*)&p[0];
        ba[1] = *(const bf16x8*)&p[8];
    };
    auto LDB = [&](int k0) {
        const float* p = &Wo[(size_t)(k0 + rl) * N + n0 + c4];
        fb[0] = *(const float4*)&p[0];  fb[1] = *(const float4*)&p[4];
        fb[2] = *(const float4*)&p[8];  fb[3] = *(const float4*)&p[12];
    };

    LDA(0); LDB(0);
    for (int k0 = 0; k0 < K; k0 += 64) {
        __syncthreads();
        *(bf16x8*)&As[rl][c4]     = ba[0];
        *(bf16x8*)&As[rl][c4 + 8] = ba[1];
        #pragma unroll
        for (int f = 0; f < 4; ++f) {
            float4 v = fb[f];
            Bs[c4 + f*4 + 0][rl] = f2b(v.x);
            Bs[c4 + f*4 + 1][rl] = f2b(v.y);
            Bs[c4 + f*4 + 2][rl] = f2b(v.z);
            Bs[c4 + f*4 + 3][rl] = f2b(v.w);
        }
        __syncthreads();

        if (k0 + 64 < K) { LDA(k0 + 64); LDB(k0 + 64); }

        bf16x8 a0 = *(const bf16x8*)&As[w * 16 + lr][quad * 8];
        bf16x8 a1 = *(const bf16x8*)&As[w * 16 + lr][32 + quad * 8];
        #pragma unroll
        for (int nt = 0; nt < 4; ++nt) {
            bf16x8 b0 = *(const bf16x8*)&Bs[nt * 16 + lr][quad * 8];
            bf16x8 b1 = *(const bf16x8*)&Bs[nt * 16 + lr][32 + quad * 8];
            acc[nt] = __builtin_amdgcn_mfma_f32_16x16x32_bf16(a0, b0, acc[nt], 0, 0, 0);
            acc[nt] = __builtin_amdgcn_mfma_f32_16x16x32_bf16(a1, b1, acc[nt], 0, 0, 0);
        }
    }

    #pragma unroll
    for (int nt = 0; nt < 4; ++nt)
        #pragma unroll
        for (int r = 0; r < 4; ++r) {
            int m = m0 + w * 16 + quad * 4 + r;
            int n = n0 + nt * 16 + lr;
            out[(size_t)m * N + n] = acc[nt][r];
        }
}

// ---------------------------------------------------------------------------
// Workspace (≈29.5 MB):
//   Qbf 2MB | Kbf 2MB | Vbf 2MB | xbar 64KB | ck 64KB | G 512KB
//   | sims 2MB (reused as Obn bf16 after topk) | lpart 320KB | cur 1KB
//   | qlist 512KB | Opart 20MB
// ---------------------------------------------------------------------------
extern "C" void kernel_launch(void* const* d_in, const int* in_sizes, int n_in,
                              void* d_out, int out_size, void* d_ws, size_t ws_size,
                              hipStream_t stream) {
    const float* x  = (const float*)d_in[0];
    const float* Wq = (const float*)d_in[1];
    const float* Wk = (const float*)d_in[2];
    const float* Wv = (const float*)d_in[3];
    const float* Wo = (const float*)d_in[4];
    float* out = (float*)d_out;

    const size_t SD = (size_t)S_LEN * D_DIM;   // 1048576
    unsigned short* Qbf = (unsigned short*)d_ws;           // [2048][512] bf16
    unsigned short* Kbf = Qbf + SD;
    unsigned short* Vbf = Kbf + SD;
    float* xbar = (float*)(Vbf + SD);                      // [32][512]
    float* ck   = xbar + (size_t)C_NUM * D_DIM;            // [32][512]
    float* G    = ck + (size_t)C_NUM * D_DIM;              // [512][256]
    float* sims = G + (size_t)D_DIM * (H_NUM * C_NUM);     // [2048][256]
    float* lpart = sims + (size_t)S_LEN * (H_NUM * C_NUM); // [5][8][2048]
    int*   curb  = (int*)(lpart + (size_t)TOPK * H_NUM * S_LEN);   // [256]
    unsigned short* qlst = (unsigned short*)(curb + 256);          // [256][QCAP]
    float* Opart = (float*)(qlst + (size_t)256 * QCAP);            // [5][8][2048][64]
    unsigned short* Obn = (unsigned short*)sims;           // reuse after topk

    dim3 pgrid(D_DIM / 64, S_LEN / 64, 4);       // Q,K,V bf16 MFMA + xbar/cur
    proj_all<<<pgrid, 256, 0, stream>>>(x, Wq, Wk, Wv, Qbf, Kbf, Vbf, xbar, curb);

    ck_kernel<<<C_NUM, 256, 0, stream>>>(xbar, Wk, ck);

    g_kernel<<<D_DIM, 256, 0, stream>>>(Wq, ck, G);

    dim3 sgrid((H_NUM * C_NUM) / BN, S_LEN / BM);  // (4, 32)
    sims_gemm<<<sgrid, 256, 0, stream>>>(x, G, sims);

    dim3 rgrid(S_LEN / 64, H_NUM);               // (32, 8)
    topk_scatter<<<rgrid, 256, 0, stream>>>(sims, curb, qlst);

    dim3 agrid(ATILES, H_NUM * C_NUM);
    moc_attn6b<<<agrid, 256, 0, stream>>>(Qbf, Kbf, Vbf, curb, qlst, lpart, Opart);

    reduce_norm<<<(int)(SD / 4 / 256), 256, 0, stream>>>((const float4*)Opart, lpart, Obn);

    dim3 ogrid(D_DIM / 64, S_LEN / 64);
    gemm_out<<<ogrid, 256, 0, stream>>>(Obn, Wo, out);
}

// Round 16
// 168.289 us; speedup vs baseline: 1.2447x; 1.0803x over previous
//
#include <hip/hip_runtime.h>
#include <hip/hip_bf16.h>
#include <math.h>

// Problem constants (B=1)
#define S_LEN 2048
#define D_DIM 512
#define H_NUM 8
#define HD    64
#define C_NUM 32
#define TOPK  5
#define SCALE 0.125f   // hd^-0.5
#define QCAP  1024     // fixed qlist capacity per (h,c); load is ~320
#define ATILES 16      // query tiles per (h,c); empties exit fast

typedef __attribute__((ext_vector_type(8))) short bf16x8;   // 8 bf16 (4 VGPRs)
typedef __attribute__((ext_vector_type(4))) float f32x4;
typedef __attribute__((ext_vector_type(4))) unsigned short us4;

__device__ __forceinline__ unsigned short f2b(float f) {
    __hip_bfloat16 h = __float2bfloat16(f);
    unsigned short u;
    __builtin_memcpy(&u, &h, 2);
    return u;
}
__device__ __forceinline__ bf16x8 pack8(float4 a, float4 b) {
    bf16x8 r;
    r[0] = (short)f2b(a.x); r[1] = (short)f2b(a.y);
    r[2] = (short)f2b(a.z); r[3] = (short)f2b(a.w);
    r[4] = (short)f2b(b.x); r[5] = (short)f2b(b.y);
    r[6] = (short)f2b(b.z); r[7] = (short)f2b(b.w);
    return r;
}
__device__ __forceinline__ float b2f(unsigned short u) {
    __hip_bfloat16 h;
    __builtin_memcpy(&h, &u, 2);
    return __bfloat162float(h);
}

// ---------------------------------------------------------------------------
// fp32 GEMM body (R12-proven, byte-identical) — used ONLY for the Q
// projection (routing-critical: sims_topk reads fp32 Q).
// ---------------------------------------------------------------------------
#define BM 64
#define BN 64
#define BK 32

__device__ __forceinline__ void gemm_body(const float* __restrict__ A,
                                          const float* __restrict__ B,
                                          float* __restrict__ C,
                                          int M, int N, int K,
                                          int bx, int by) {
    __shared__ float As[BK][BM + 4];
    __shared__ float Bs[BK][BN];

    const int t  = threadIdx.x;
    const int tx = t & 15;
    const int ty = t >> 4;
    const int m0 = by * BM;
    const int n0 = bx * BN;

    float4 acc0 = make_float4(0.f,0.f,0.f,0.f);
    float4 acc1 = make_float4(0.f,0.f,0.f,0.f);
    float4 acc2 = make_float4(0.f,0.f,0.f,0.f);
    float4 acc3 = make_float4(0.f,0.f,0.f,0.f);

    const int ar = t >> 3;
    const int ac = (t & 7) * 4;
    const int br = t >> 4;
    const int bc = (t & 15) * 4;

    float4 a0, a1, b0, b1;
    auto LD = [&](int k0) {
        a0 = *(const float4*)&A[(size_t)(m0 + ar)      * K + k0 + ac];
        a1 = *(const float4*)&A[(size_t)(m0 + ar + 32) * K + k0 + ac];
        b0 = *(const float4*)&B[(size_t)(k0 + br)      * N + n0 + bc];
        b1 = *(const float4*)&B[(size_t)(k0 + br + 16) * N + n0 + bc];
    };

    LD(0);
    for (int k0 = 0; k0 < K; k0 += BK) {
        __syncthreads();
        As[ac+0][ar]    = a0.x; As[ac+1][ar]    = a0.y; As[ac+2][ar]    = a0.z; As[ac+3][ar]    = a0.w;
        As[ac+0][ar+32] = a1.x; As[ac+1][ar+32] = a1.y; As[ac+2][ar+32] = a1.z; As[ac+3][ar+32] = a1.w;
        *(float4*)&Bs[br][bc]      = b0;
        *(float4*)&Bs[br + 16][bc] = b1;
        __syncthreads();

        if (k0 + BK < K) LD(k0 + BK);

        #pragma unroll
        for (int kk = 0; kk < BK; ++kk) {
            float4 a = *(const float4*)&As[kk][ty * 4];
            float4 b = *(const float4*)&Bs[kk][tx * 4];
            acc0.x += a.x*b.x; acc0.y += a.x*b.y; acc0.z += a.x*b.z; acc0.w += a.x*b.w;
            acc1.x += a.y*b.x; acc1.y += a.y*b.y; acc1.z += a.y*b.z; acc1.w += a.y*b.w;
            acc2.x += a.z*b.x; acc2.y += a.z*b.y; acc2.z += a.z*b.z; acc2.w += a.z*b.w;
            acc3.x += a.w*b.x; acc3.y += a.w*b.y; acc3.z += a.w*b.z; acc3.w += a.w*b.w;
        }
    }

    *(float4*)&C[(size_t)(m0 + ty*4 + 0) * N + n0 + tx*4] = acc0;
    *(float4*)&C[(size_t)(m0 + ty*4 + 1) * N + n0 + tx*4] = acc1;
    *(float4*)&C[(size_t)(m0 + ty*4 + 2) * N + n0 + tx*4] = acc2;
    *(float4*)&C[(size_t)(m0 + ty*4 + 3) * N + n0 + tx*4] = acc3;
}

// ---------------------------------------------------------------------------
// bf16 MFMA GEMM body (fp32 A, fp32 B, bf16 C). R11/R12-proven.
// ---------------------------------------------------------------------------
__device__ __forceinline__ void gemm_v_body(const float* __restrict__ A,
                                            const float* __restrict__ B,
                                            unsigned short* __restrict__ C,
                                            int M, int N, int K,
                                            int bx, int by) {
    __shared__ unsigned short Asv[64][72];
    __shared__ unsigned short Bsv[64][72];

    const int t  = threadIdx.x;
    const int m0 = by * 64;
    const int n0 = bx * 64;
    const int rl = t >> 2;
    const int c4 = (t & 3) * 16;

    const int lane = t & 63, w = t >> 6, lr = lane & 15, quad = lane >> 4;

    f32x4 acc[4] = {{0.f,0.f,0.f,0.f},{0.f,0.f,0.f,0.f},
                    {0.f,0.f,0.f,0.f},{0.f,0.f,0.f,0.f}};

    float4 fa[4], fb[4];
    auto LDA = [&](int k0) {
        const float* p = &A[(size_t)(m0 + rl) * K + k0 + c4];
        fa[0] = *(const float4*)&p[0];  fa[1] = *(const float4*)&p[4];
        fa[2] = *(const float4*)&p[8];  fa[3] = *(const float4*)&p[12];
    };
    auto LDB = [&](int k0) {
        const float* p = &B[(size_t)(k0 + rl) * N + n0 + c4];
        fb[0] = *(const float4*)&p[0];  fb[1] = *(const float4*)&p[4];
        fb[2] = *(const float4*)&p[8];  fb[3] = *(const float4*)&p[12];
    };

    LDA(0); LDB(0);
    for (int k0 = 0; k0 < K; k0 += 64) {
        __syncthreads();
        *(bf16x8*)&Asv[rl][c4]     = pack8(fa[0], fa[1]);
        *(bf16x8*)&Asv[rl][c4 + 8] = pack8(fa[2], fa[3]);
        #pragma unroll
        for (int f = 0; f < 4; ++f) {   // B transpose: Bsv[n][k]
            float4 v = fb[f];
            Bsv[c4 + f*4 + 0][rl] = f2b(v.x);
            Bsv[c4 + f*4 + 1][rl] = f2b(v.y);
            Bsv[c4 + f*4 + 2][rl] = f2b(v.z);
            Bsv[c4 + f*4 + 3][rl] = f2b(v.w);
        }
        __syncthreads();

        if (k0 + 64 < K) { LDA(k0 + 64); LDB(k0 + 64); }

        bf16x8 a0 = *(const bf16x8*)&Asv[w * 16 + lr][quad * 8];
        bf16x8 a1 = *(const bf16x8*)&Asv[w * 16 + lr][32 + quad * 8];
        #pragma unroll
        for (int nt = 0; nt < 4; ++nt) {
            bf16x8 b0 = *(const bf16x8*)&Bsv[nt * 16 + lr][quad * 8];
            bf16x8 b1 = *(const bf16x8*)&Bsv[nt * 16 + lr][32 + quad * 8];
            acc[nt] = __builtin_amdgcn_mfma_f32_16x16x32_bf16(a0, b0, acc[nt], 0, 0, 0);
            acc[nt] = __builtin_amdgcn_mfma_f32_16x16x32_bf16(a1, b1, acc[nt], 0, 0, 0);
        }
    }

    #pragma unroll
    for (int nt = 0; nt < 4; ++nt)
        #pragma unroll
        for (int r = 0; r < 4; ++r) {
            int m = m0 + w * 16 + quad * 4 + r;
            int n = n0 + nt * 16 + lr;
            C[(size_t)m * N + n] = f2b(acc[nt][r]);
        }
}

// ---------------------------------------------------------------------------
// One projection dispatch: z=0 Q fp32 (routing-exact), z=1 K bf16 MFMA,
// z=2 V bf16 MFMA, z=3 xbar (per-chunk mean of x, fp32; R15-proven shape)
// + routing-counter zeroing. K no longer needs fp32: ck comes from xbar.
// ---------------------------------------------------------------------------
__global__ __launch_bounds__(256) void proj4(const float* __restrict__ x,
                                             const float* __restrict__ Wq,
                                             const float* __restrict__ Wk,
                                             const float* __restrict__ Wv,
                                             float* __restrict__ Qf,
                                             unsigned short* __restrict__ Kbf,
                                             unsigned short* __restrict__ Vbf,
                                             float* __restrict__ xbar,
                                             int* __restrict__ cur) {
    if (blockIdx.z == 0) {
        gemm_body(x, Wq, Qf, S_LEN, D_DIM, D_DIM, blockIdx.x, blockIdx.y);
    } else if (blockIdx.z == 1) {
        gemm_v_body(x, Wk, Kbf, S_LEN, D_DIM, D_DIM, blockIdx.x, blockIdx.y);
    } else if (blockIdx.z == 2) {
        gemm_v_body(x, Wv, Vbf, S_LEN, D_DIM, D_DIM, blockIdx.x, blockIdx.y);
    } else {
        int t = threadIdx.x;
        if (blockIdx.x == 0 && blockIdx.y == 0) cur[t] = 0;
        int flat = (blockIdx.y * 8 + blockIdx.x) * 256 + t;
        if (flat < C_NUM * D_DIM) {
            int c = flat >> 9, d = flat & 511;
            const float* p = x + (size_t)c * 64 * D_DIM + d;
            float s = 0.f;
            #pragma unroll
            for (int r = 0; r < 64; ++r) s += p[(size_t)r * D_DIM];
            xbar[flat] = s * (1.0f / 64.0f);
        }
    }
}

// ---------------------------------------------------------------------------
// ck[c][:] = xbar[c] @ Wk   (fp32; R15-proven bytes)
// ---------------------------------------------------------------------------
__global__ __launch_bounds__(256) void ck_kernel(const float* __restrict__ xbar,
                                                 const float* __restrict__ Wk,
                                                 float* __restrict__ ck) {
    __shared__ float xl[512];
    const int c = blockIdx.x, t = threadIdx.x;
    xl[t]       = xbar[c * 512 + t];
    xl[t + 256] = xbar[c * 512 + t + 256];
    __syncthreads();
    float s0 = 0.f, s1 = 0.f;
    #pragma unroll 8
    for (int j = 0; j < 512; ++j) {
        float xv = xl[j];
        s0 += xv * Wk[(size_t)j * 512 + t];
        s1 += xv * Wk[(size_t)j * 512 + t + 256];
    }
    ck[c * 512 + t]       = s0;
    ck[c * 512 + t + 256] = s1;
}

// ---------------------------------------------------------------------------
// Fused sims + top-5 + scatter (R12-proven bytes: fp32 Q . ck per head,
// strict-> scan == jax tie-break; rank k packed into qlist bits 11..13).
// ---------------------------------------------------------------------------
__global__ __launch_bounds__(256) void sims_topk(const float* __restrict__ Q,
                                                 const float* __restrict__ ck,
                                                 int* __restrict__ cur,
                                                 unsigned short* __restrict__ qlist) {
    __shared__ float qtile[64][68];
    __shared__ float cks[32][68];
    __shared__ float simsb[64][36];
    __shared__ int   lds_cnt[32];
    __shared__ int   lds_base[32];

    const int t  = threadIdx.x;
    const int s0 = blockIdx.x * 64;
    const int h  = blockIdx.y;

    if (t < 32) lds_cnt[t] = 0;

    {
        int r = t >> 2;
        #pragma unroll
        for (int i = 0; i < 4; ++i) {
            int cf4 = (t & 3) * 4 + i;
            *(float4*)&qtile[r][cf4 * 4] =
                *(const float4*)&Q[(size_t)(s0 + r) * D_DIM + h * HD + cf4 * 4];
        }
    }
    for (int i = t; i < C_NUM * 16; i += 256) {
        int c = i >> 4, df4 = i & 15;
        *(float4*)&cks[c][df4 * 4] =
            *(const float4*)&ck[(size_t)c * D_DIM + h * HD + df4 * 4];
    }
    __syncthreads();

    {
        const int sl = t >> 2, g = t & 3;
        float sa[8] = {0.f,0.f,0.f,0.f,0.f,0.f,0.f,0.f};
        #pragma unroll
        for (int d4 = 0; d4 < 16; ++d4) {
            float4 q4 = *(const float4*)&qtile[sl][d4 * 4];
            #pragma unroll
            for (int j = 0; j < 8; ++j) {
                float4 c4 = *(const float4*)&cks[g * 8 + j][d4 * 4];
                sa[j] += q4.x*c4.x + q4.y*c4.y + q4.z*c4.z + q4.w*c4.w;
            }
        }
        *(float4*)&simsb[sl][g*8 + 0] = make_float4(sa[0], sa[1], sa[2], sa[3]);
        *(float4*)&simsb[sl][g*8 + 4] = make_float4(sa[4], sa[5], sa[6], sa[7]);
    }
    __syncthreads();

    int csel[TOPK], lpos[TOPK];
    if (t < 64) {
        float sv[32];
        #pragma unroll
        for (int cq = 0; cq < 8; ++cq) {
            float4 v = *(const float4*)&simsb[t][cq * 4];
            sv[cq*4+0] = v.x; sv[cq*4+1] = v.y; sv[cq*4+2] = v.z; sv[cq*4+3] = v.w;
        }
        #pragma unroll
        for (int k = 0; k < TOPK; ++k) {
            float best = -INFINITY; int bi = 0;
            #pragma unroll
            for (int cc = 0; cc < 32; ++cc) {
                bool gt = sv[cc] > best;
                best = gt ? sv[cc] : best;
                bi   = gt ? cc : bi;
            }
            #pragma unroll
            for (int cc = 0; cc < 32; ++cc)
                if (cc == bi) sv[cc] = -INFINITY;
            csel[k] = bi;
            lpos[k] = atomicAdd(&lds_cnt[bi], 1);
        }
    }
    __syncthreads();

    if (t < 32) lds_base[t] = atomicAdd(&cur[h * 32 + t], lds_cnt[t]);
    __syncthreads();

    if (t < 64) {
        #pragma unroll
        for (int k = 0; k < TOPK; ++k) {
            int c = csel[k];
            int pos = lds_base[c] + lpos[k];
            if (pos < QCAP)
                qlist[(size_t)(h * 32 + c) * QCAP + pos] =
                    (unsigned short)((s0 + t) | (k << 11));
        }
    }
}

// ---------------------------------------------------------------------------
// MFMA chunk-centric attention (v6c): fp32 Q staging (R12-proven pack8) +
// bf16 K/V staging (R15-proven). One block barrier; unique-writer stores.
// ---------------------------------------------------------------------------
__global__ __launch_bounds__(256) void moc_attn6c(const float* __restrict__ Qf,
                                                  const unsigned short* __restrict__ Kbf,
                                                  const unsigned short* __restrict__ Vbf,
                                                  const int* __restrict__ cnt,
                                                  const unsigned short* __restrict__ qlist,
                                                  float* __restrict__ lpart,
                                                  float* __restrict__ Opart) {
    __shared__ unsigned short Qs[64][72];
    __shared__ unsigned short Ks[64][72];
    __shared__ unsigned short VT[64][72];
    __shared__ unsigned short Ps[64][72];
    __shared__ unsigned short slist[64];

    const int hc = blockIdx.y;
    const int h  = hc >> 5;
    const int c  = hc & 31;
    const int g  = blockIdx.x;
    const int t  = threadIdx.x;

    const int count = min(cnt[hc], QCAP);
    const int base  = g * 64;
    if (base >= count) return;
    const int lim = min(count - base, 64);

    const unsigned short* Kb = Kbf + ((size_t)c * 64) * D_DIM + h * HD;
    const unsigned short* Vb = Vbf + ((size_t)c * 64) * D_DIM + h * HD;
    const unsigned short* list = qlist + (size_t)hc * QCAP + base;

    {
        const int j  = t >> 2;
        const int d0 = (t & 3) * 16;

        const unsigned short* kr = Kb + (size_t)j * D_DIM + d0;
        *(bf16x8*)&Ks[j][d0]     = *(const bf16x8*)&kr[0];
        *(bf16x8*)&Ks[j][d0 + 8] = *(const bf16x8*)&kr[8];

        const unsigned short* vr = Vb + (size_t)j * D_DIM + d0;
        bf16x8 v0 = *(const bf16x8*)&vr[0];
        bf16x8 v1 = *(const bf16x8*)&vr[8];
        #pragma unroll
        for (int i = 0; i < 8; ++i) {
            VT[d0 + i][j]     = (unsigned short)v0[i];
            VT[d0 + 8 + i][j] = (unsigned short)v1[i];
        }

        unsigned short pv = (j < lim) ? list[j] : (unsigned short)0xFFFF;
        if ((t & 3) == 0) slist[j] = pv;
        int s = (pv == 0xFFFF) ? 0 : (int)(pv & 2047);
        const float* qr = Qf + (size_t)s * D_DIM + h * HD + d0;
        float4 q0 = *(const float4*)&qr[0],  q1 = *(const float4*)&qr[4];
        float4 q2 = *(const float4*)&qr[8],  q3 = *(const float4*)&qr[12];
        *(bf16x8*)&Qs[j][d0]     = pack8(q0, q1);
        *(bf16x8*)&Qs[j][d0 + 8] = pack8(q2, q3);
    }
    __syncthreads();

    const int lane = t & 63;
    const int w    = t >> 6;
    const int lr   = lane & 15;
    const int quad = lane >> 4;

    bf16x8 aq0 = *(const bf16x8*)&Qs[w * 16 + lr][quad * 8];
    bf16x8 aq1 = *(const bf16x8*)&Qs[w * 16 + lr][32 + quad * 8];

    f32x4 acc[4];
    #pragma unroll
    for (int kt = 0; kt < 4; ++kt) {
        bf16x8 b0 = *(const bf16x8*)&Ks[kt * 16 + lr][quad * 8];
        bf16x8 b1 = *(const bf16x8*)&Ks[kt * 16 + lr][32 + quad * 8];
        f32x4 z = {0.f, 0.f, 0.f, 0.f};
        z = __builtin_amdgcn_mfma_f32_16x16x32_bf16(aq0, b0, z, 0, 0, 0);
        z = __builtin_amdgcn_mfma_f32_16x16x32_bf16(aq1, b1, z, 0, 0, 0);
        acc[kt] = z;
    }

    unsigned short pb[4][4];
    float dsum[4] = {0.f, 0.f, 0.f, 0.f};
    #pragma unroll
    for (int kt = 0; kt < 4; ++kt) {
        #pragma unroll
        for (int r = 0; r < 4; ++r) {
            unsigned short u = f2b(__expf(acc[kt][r] * SCALE));
            pb[kt][r] = u;
            dsum[r] += b2f(u);
        }
    }
    #pragma unroll
    for (int r = 0; r < 4; ++r) {
        float v = dsum[r];
        v += __shfl_xor(v, 1, 64);
        v += __shfl_xor(v, 2, 64);
        v += __shfl_xor(v, 4, 64);
        v += __shfl_xor(v, 8, 64);
        dsum[r] = v;
    }
    if (lr == 0) {
        #pragma unroll
        for (int r = 0; r < 4; ++r) {
            unsigned short sv = slist[w * 16 + quad * 4 + r];
            if (sv != 0xFFFF) {
                int kk = sv >> 11, s = sv & 2047;
                lpart[((size_t)kk * H_NUM + h) * S_LEN + s] = dsum[r];
            }
        }
    }

    #pragma unroll
    for (int kt = 0; kt < 4; ++kt)
        #pragma unroll
        for (int r = 0; r < 4; ++r)
            Ps[w * 16 + quad * 4 + r][kt * 16 + lr] = pb[kt][r];

    bf16x8 ap0 = *(const bf16x8*)&Ps[w * 16 + lr][quad * 8];
    bf16x8 ap1 = *(const bf16x8*)&Ps[w * 16 + lr][32 + quad * 8];

    #pragma unroll
    for (int dt = 0; dt < 4; ++dt) {
        bf16x8 b0 = *(const bf16x8*)&VT[dt * 16 + lr][quad * 8];
        bf16x8 b1 = *(const bf16x8*)&VT[dt * 16 + lr][32 + quad * 8];
        f32x4 z = {0.f, 0.f, 0.f, 0.f};
        z = __builtin_amdgcn_mfma_f32_16x16x32_bf16(ap0, b0, z, 0, 0, 0);
        z = __builtin_amdgcn_mfma_f32_16x16x32_bf16(ap1, b1, z, 0, 0, 0);
        #pragma unroll
        for (int r = 0; r < 4; ++r) {
            unsigned short sv = slist[w * 16 + quad * 4 + r];
            if (sv != 0xFFFF) {
                int kk = sv >> 11, s = sv & 2047;
                Opart[((((size_t)kk * H_NUM + h) * S_LEN + s) * HD) + dt * 16 + lr] = z[r];
            }
        }
    }
}

// ---------------------------------------------------------------------------
// Obn_bf[s][h*64+d] = bf16( (sum_k Opart[k][h][s][d]) / (sum_k lpart) )
// ---------------------------------------------------------------------------
__global__ __launch_bounds__(256) void reduce_norm(const float4* __restrict__ Opart4,
                                                   const float* __restrict__ lpart,
                                                   unsigned short* __restrict__ Obn) {
    int i = blockIdx.x * 256 + threadIdx.x;
    int s    = i >> 7;
    int col4 = i & 127;
    int h    = col4 >> 4;
    int f4   = col4 & 15;
    float4 acc = make_float4(0.f,0.f,0.f,0.f);
    float  den = 0.f;
    #pragma unroll
    for (int k = 0; k < TOPK; ++k) {
        size_t slot = ((size_t)k * H_NUM + h) * S_LEN + s;
        float4 v = Opart4[slot * 16 + f4];
        acc.x += v.x; acc.y += v.y; acc.z += v.z; acc.w += v.w;
        den += lpart[slot];
    }
    float inv = 1.0f / den;
    us4 o;
    o[0] = f2b(acc.x * inv); o[1] = f2b(acc.y * inv);
    o[2] = f2b(acc.z * inv); o[3] = f2b(acc.w * inv);
    *(us4*)&Obn[(size_t)i * 4] = o;
}

// ---------------------------------------------------------------------------
// Output projection: bf16 A (normalized attention out), fp32 C (MFMA).
// ---------------------------------------------------------------------------
__global__ __launch_bounds__(256) void gemm_out(const unsigned short* __restrict__ Obn,
                                                const float* __restrict__ Wo,
                                                float* __restrict__ out) {
    __shared__ unsigned short As[64][72];
    __shared__ unsigned short Bs[64][72];

    const int t  = threadIdx.x;
    const int m0 = blockIdx.y * 64;
    const int n0 = blockIdx.x * 64;
    const int rl = t >> 2;
    const int c4 = (t & 3) * 16;
    const int N = D_DIM, K = D_DIM;

    const int lane = t & 63, w = t >> 6, lr = lane & 15, quad = lane >> 4;

    f32x4 acc[4] = {{0.f,0.f,0.f,0.f},{0.f,0.f,0.f,0.f},
                    {0.f,0.f,0.f,0.f},{0.f,0.f,0.f,0.f}};

    bf16x8 ba[2]; float4 fb[4];
    auto LDA = [&](int k0) {
        const unsigned short* p = &Obn[(size_t)(m0 + rl) * K + k0 + c4];
        ba[0] = *(const bf16x8*)&p[0];
        ba[1] = *(const bf16x8*)&p[8];
    };
    auto LDB = [&](int k0) {
        const float* p = &Wo[(size_t)(k0 + rl) * N + n0 + c4];
        fb[0] = *(const float4*)&p[0];  fb[1] = *(const float4*)&p[4];
        fb[2] = *(const float4*)&p[8];  fb[3] = *(const float4*)&p[12];
    };

    LDA(0); LDB(0);
    for (int k0 = 0; k0 < K; k0 += 64) {
        __syncthreads();
        *(bf16x8*)&As[rl][c4]     = ba[0];
        *(bf16x8*)&As[rl][c4 + 8] = ba[1];
        #pragma unroll
        for (int f = 0; f < 4; ++f) {
            float4 v = fb[f];
            Bs[c4 + f*4 + 0][rl] = f2b(v.x);
            Bs[c4 + f*4 + 1][rl] = f2b(v.y);
            Bs[c4 + f*4 + 2][rl] = f2b(v.z);
            Bs[c4 + f*4 + 3][rl] = f2b(v.w);
        }
        __syncthreads();

        if (k0 + 64 < K) { LDA(k0 + 64); LDB(k0 + 64); }

        bf16x8 a0 = *(const bf16x8*)&As[w * 16 + lr][quad * 8];
        bf16x8 a1 = *(const bf16x8*)&As[w * 16 + lr][32 + quad * 8];
        #pragma unroll
        for (int nt = 0; nt < 4; ++nt) {
            bf16x8 b0 = *(const bf16x8*)&Bs[nt * 16 + lr][quad * 8];
            bf16x8 b1 = *(const bf16x8*)&Bs[nt * 16 + lr][32 + quad * 8];
            acc[nt] = __builtin_amdgcn_mfma_f32_16x16x32_bf16(a0, b0, acc[nt], 0, 0, 0);
            acc[nt] = __builtin_amdgcn_mfma_f32_16x16x32_bf16(a1, b1, acc[nt], 0, 0, 0);
        }
    }

    #pragma unroll
    for (int nt = 0; nt < 4; ++nt)
        #pragma unroll
        for (int r = 0; r < 4; ++r) {
            int m = m0 + w * 16 + quad * 4 + r;
            int n = n0 + nt * 16 + lr;
            out[(size_t)m * N + n] = acc[nt][r];
        }
}

// ---------------------------------------------------------------------------
// Workspace (~29 MB):
//   Qf fp32 4MB (reused as Obn bf16 after attention) | Kbf 2MB | Vbf 2MB
//   | xbar 64KB | ck 64KB | lpart 320KB | cur 1KB | qlist 512KB | Opart 20MB
// ---------------------------------------------------------------------------
extern "C" void kernel_launch(void* const* d_in, const int* in_sizes, int n_in,
                              void* d_out, int out_size, void* d_ws, size_t ws_size,
                              hipStream_t stream) {
    const float* x  = (const float*)d_in[0];
    const float* Wq = (const float*)d_in[1];
    const float* Wk = (const float*)d_in[2];
    const float* Wv = (const float*)d_in[3];
    const float* Wo = (const float*)d_in[4];
    float* out = (float*)d_out;

    const size_t SD = (size_t)S_LEN * D_DIM;   // 1048576
    float* Qf = (float*)d_ws;                              // [2048][512] fp32
    unsigned short* Kbf = (unsigned short*)(Qf + SD);      // [2048][512] bf16
    unsigned short* Vbf = Kbf + SD;                        // [2048][512] bf16
    float* xbar = (float*)(Vbf + SD);                      // [32][512]
    float* ck   = xbar + (size_t)C_NUM * D_DIM;            // [32][512]
    float* lpart = ck + (size_t)C_NUM * D_DIM;             // [5][8][2048]
    int*   curb  = (int*)(lpart + (size_t)TOPK * H_NUM * S_LEN);   // [256]
    unsigned short* qlst = (unsigned short*)(curb + 256);          // [256][QCAP]
    float* Opart = (float*)(qlst + (size_t)256 * QCAP);            // [5][8][2048][64]
    unsigned short* Obn = (unsigned short*)Qf;             // reuse after attention

    dim3 pgrid(D_DIM / 64, S_LEN / 64, 4);       // Q fp32, K/V MFMA, xbar/cur
    proj4<<<pgrid, 256, 0, stream>>>(x, Wq, Wk, Wv, Qf, Kbf, Vbf, xbar, curb);

    ck_kernel<<<C_NUM, 256, 0, stream>>>(xbar, Wk, ck);

    dim3 rgrid(S_LEN / 64, H_NUM);               // (32, 8)
    sims_topk<<<rgrid, 256, 0, stream>>>(Qf, ck, curb, qlst);

    dim3 agrid(ATILES, H_NUM * C_NUM);           // (16, 256); empties exit
    moc_attn6c<<<agrid, 256, 0, stream>>>(Qf, Kbf, Vbf, curb, qlst, lpart, Opart);

    reduce_norm<<<(int)(SD / 4 / 256), 256, 0, stream>>>((const float4*)Opart, lpart, Obn);

    dim3 ogrid(D_DIM / 64, S_LEN / 64);
    gemm_out<<<ogrid, 256, 0, stream>>>(Obn, Wo, out);
}

// Round 17
// 167.103 us; speedup vs baseline: 1.2535x; 1.0071x over previous
//
#include <hip/hip_runtime.h>
#include <hip/hip_bf16.h>
#include <math.h>

// Problem constants (B=1)
#define S_LEN 2048
#define D_DIM 512
#define H_NUM 8
#define HD    64
#define C_NUM 32
#define TOPK  5
#define SCALE 0.125f   // hd^-0.5
#define QCAP  1024     // fixed qlist capacity per (h,c); load is ~320
#define ATILES 16      // query tiles per (h,c); empties exit fast

typedef __attribute__((ext_vector_type(8))) short bf16x8;   // 8 bf16 (4 VGPRs)
typedef __attribute__((ext_vector_type(4))) float f32x4;
typedef __attribute__((ext_vector_type(4))) unsigned short us4;

__device__ __forceinline__ unsigned short f2b(float f) {
    __hip_bfloat16 h = __float2bfloat16(f);
    unsigned short u;
    __builtin_memcpy(&u, &h, 2);
    return u;
}
__device__ __forceinline__ bf16x8 pack8(float4 a, float4 b) {
    bf16x8 r;
    r[0] = (short)f2b(a.x); r[1] = (short)f2b(a.y);
    r[2] = (short)f2b(a.z); r[3] = (short)f2b(a.w);
    r[4] = (short)f2b(b.x); r[5] = (short)f2b(b.y);
    r[6] = (short)f2b(b.z); r[7] = (short)f2b(b.w);
    return r;
}
__device__ __forceinline__ float b2f(unsigned short u) {
    __hip_bfloat16 h;
    __builtin_memcpy(&h, &u, 2);
    return __bfloat162float(h);
}

// ---------------------------------------------------------------------------
// fp32 GEMM body (R12-proven, byte-identical) — Q projection ONLY, in its
// own kernel (twice-confirmed lesson: fusing this with the MFMA body makes
// the union of LDS/VGPR and kills fp32-block occupancy).
// ---------------------------------------------------------------------------
#define BM 64
#define BN 64
#define BK 32

__global__ __launch_bounds__(256) void gemm_q(const float* __restrict__ A,
                                              const float* __restrict__ B,
                                              float* __restrict__ C) {
    __shared__ float As[BK][BM + 4];
    __shared__ float Bs[BK][BN];

    const int t  = threadIdx.x;
    const int tx = t & 15;
    const int ty = t >> 4;
    const int m0 = blockIdx.y * BM;
    const int n0 = blockIdx.x * BN;
    const int N = D_DIM, K = D_DIM;

    float4 acc0 = make_float4(0.f,0.f,0.f,0.f);
    float4 acc1 = make_float4(0.f,0.f,0.f,0.f);
    float4 acc2 = make_float4(0.f,0.f,0.f,0.f);
    float4 acc3 = make_float4(0.f,0.f,0.f,0.f);

    const int ar = t >> 3;
    const int ac = (t & 7) * 4;
    const int br = t >> 4;
    const int bc = (t & 15) * 4;

    float4 a0, a1, b0, b1;
    auto LD = [&](int k0) {
        a0 = *(const float4*)&A[(size_t)(m0 + ar)      * K + k0 + ac];
        a1 = *(const float4*)&A[(size_t)(m0 + ar + 32) * K + k0 + ac];
        b0 = *(const float4*)&B[(size_t)(k0 + br)      * N + n0 + bc];
        b1 = *(const float4*)&B[(size_t)(k0 + br + 16) * N + n0 + bc];
    };

    LD(0);
    for (int k0 = 0; k0 < K; k0 += BK) {
        __syncthreads();
        As[ac+0][ar]    = a0.x; As[ac+1][ar]    = a0.y; As[ac+2][ar]    = a0.z; As[ac+3][ar]    = a0.w;
        As[ac+0][ar+32] = a1.x; As[ac+1][ar+32] = a1.y; As[ac+2][ar+32] = a1.z; As[ac+3][ar+32] = a1.w;
        *(float4*)&Bs[br][bc]      = b0;
        *(float4*)&Bs[br + 16][bc] = b1;
        __syncthreads();

        if (k0 + BK < K) LD(k0 + BK);

        #pragma unroll
        for (int kk = 0; kk < BK; ++kk) {
            float4 a = *(const float4*)&As[kk][ty * 4];
            float4 b = *(const float4*)&Bs[kk][tx * 4];
            acc0.x += a.x*b.x; acc0.y += a.x*b.y; acc0.z += a.x*b.z; acc0.w += a.x*b.w;
            acc1.x += a.y*b.x; acc1.y += a.y*b.y; acc1.z += a.y*b.z; acc1.w += a.y*b.w;
            acc2.x += a.z*b.x; acc2.y += a.z*b.y; acc2.z += a.z*b.z; acc2.w += a.z*b.w;
            acc3.x += a.w*b.x; acc3.y += a.w*b.y; acc3.z += a.w*b.z; acc3.w += a.w*b.w;
        }
    }

    *(float4*)&C[(size_t)(m0 + ty*4 + 0) * N + n0 + tx*4] = acc0;
    *(float4*)&C[(size_t)(m0 + ty*4 + 1) * N + n0 + tx*4] = acc1;
    *(float4*)&C[(size_t)(m0 + ty*4 + 2) * N + n0 + tx*4] = acc2;
    *(float4*)&C[(size_t)(m0 + ty*4 + 3) * N + n0 + tx*4] = acc3;
}

// ---------------------------------------------------------------------------
// bf16 MFMA GEMM body (fp32 A, fp32 B, bf16 C). R11/R12-proven.
// ---------------------------------------------------------------------------
__device__ __forceinline__ void gemm_v_body(const float* __restrict__ A,
                                            const float* __restrict__ B,
                                            unsigned short* __restrict__ C,
                                            int M, int N, int K,
                                            int bx, int by) {
    __shared__ unsigned short Asv[64][72];
    __shared__ unsigned short Bsv[64][72];

    const int t  = threadIdx.x;
    const int m0 = by * 64;
    const int n0 = bx * 64;
    const int rl = t >> 2;
    const int c4 = (t & 3) * 16;

    const int lane = t & 63, w = t >> 6, lr = lane & 15, quad = lane >> 4;

    f32x4 acc[4] = {{0.f,0.f,0.f,0.f},{0.f,0.f,0.f,0.f},
                    {0.f,0.f,0.f,0.f},{0.f,0.f,0.f,0.f}};

    float4 fa[4], fb[4];
    auto LDA = [&](int k0) {
        const float* p = &A[(size_t)(m0 + rl) * K + k0 + c4];
        fa[0] = *(const float4*)&p[0];  fa[1] = *(const float4*)&p[4];
        fa[2] = *(const float4*)&p[8];  fa[3] = *(const float4*)&p[12];
    };
    auto LDB = [&](int k0) {
        const float* p = &B[(size_t)(k0 + rl) * N + n0 + c4];
        fb[0] = *(const float4*)&p[0];  fb[1] = *(const float4*)&p[4];
        fb[2] = *(const float4*)&p[8];  fb[3] = *(const float4*)&p[12];
    };

    LDA(0); LDB(0);
    for (int k0 = 0; k0 < K; k0 += 64) {
        __syncthreads();
        *(bf16x8*)&Asv[rl][c4]     = pack8(fa[0], fa[1]);
        *(bf16x8*)&Asv[rl][c4 + 8] = pack8(fa[2], fa[3]);
        #pragma unroll
        for (int f = 0; f < 4; ++f) {   // B transpose: Bsv[n][k]
            float4 v = fb[f];
            Bsv[c4 + f*4 + 0][rl] = f2b(v.x);
            Bsv[c4 + f*4 + 1][rl] = f2b(v.y);
            Bsv[c4 + f*4 + 2][rl] = f2b(v.z);
            Bsv[c4 + f*4 + 3][rl] = f2b(v.w);
        }
        __syncthreads();

        if (k0 + 64 < K) { LDA(k0 + 64); LDB(k0 + 64); }

        bf16x8 a0 = *(const bf16x8*)&Asv[w * 16 + lr][quad * 8];
        bf16x8 a1 = *(const bf16x8*)&Asv[w * 16 + lr][32 + quad * 8];
        #pragma unroll
        for (int nt = 0; nt < 4; ++nt) {
            bf16x8 b0 = *(const bf16x8*)&Bsv[nt * 16 + lr][quad * 8];
            bf16x8 b1 = *(const bf16x8*)&Bsv[nt * 16 + lr][32 + quad * 8];
            acc[nt] = __builtin_amdgcn_mfma_f32_16x16x32_bf16(a0, b0, acc[nt], 0, 0, 0);
            acc[nt] = __builtin_amdgcn_mfma_f32_16x16x32_bf16(a1, b1, acc[nt], 0, 0, 0);
        }
    }

    #pragma unroll
    for (int nt = 0; nt < 4; ++nt)
        #pragma unroll
        for (int r = 0; r < 4; ++r) {
            int m = m0 + w * 16 + quad * 4 + r;
            int n = n0 + nt * 16 + lr;
            C[(size_t)m * N + n] = f2b(acc[nt][r]);
        }
}

// ---------------------------------------------------------------------------
// K + V bf16 MFMA projections (z=0/1) with the routing chunk-descriptor
// chain folded into z=2: 32 working blocks compute ck[c] = xbar[c] @ Wk
// (xbar built in-LDS with the same r-ascending sum as R15/R16 -> ck bytes
// identical) + routing-counter zeroing. ck branch uses 2 KB LDS -> no
// meaningful resource union with the MFMA body.
// ---------------------------------------------------------------------------
__global__ __launch_bounds__(256) void gemm_kv_ck(const float* __restrict__ x,
                                                  const float* __restrict__ Wk,
                                                  const float* __restrict__ Wv,
                                                  unsigned short* __restrict__ Kbf,
                                                  unsigned short* __restrict__ Vbf,
                                                  float* __restrict__ ck,
                                                  int* __restrict__ cur) {
    if (blockIdx.z == 2) {
        if (blockIdx.x != 0) return;          // 32 working blocks (by = chunk)
        __shared__ float xl[512];
        const int c = blockIdx.y;
        const int t = threadIdx.x;
        if (c == 0) cur[t] = 0;

        const float* xp = x + (size_t)c * 64 * D_DIM;
        float s0 = 0.f, s1 = 0.f;
        #pragma unroll
        for (int r = 0; r < 64; ++r) {
            s0 += xp[(size_t)r * D_DIM + t];
            s1 += xp[(size_t)r * D_DIM + t + 256];
        }
        xl[t]       = s0 * (1.0f / 64.0f);
        xl[t + 256] = s1 * (1.0f / 64.0f);
        __syncthreads();

        float a0 = 0.f, a1 = 0.f;
        #pragma unroll 8
        for (int j = 0; j < 512; ++j) {
            float xv = xl[j];
            a0 += xv * Wk[(size_t)j * 512 + t];
            a1 += xv * Wk[(size_t)j * 512 + t + 256];
        }
        ck[c * 512 + t]       = a0;
        ck[c * 512 + t + 256] = a1;
        return;
    }
    const float* W = (blockIdx.z == 0) ? Wk : Wv;
    unsigned short* C = (blockIdx.z == 0) ? Kbf : Vbf;
    gemm_v_body(x, W, C, S_LEN, D_DIM, D_DIM, blockIdx.x, blockIdx.y);
}

// ---------------------------------------------------------------------------
// Fused sims + top-5 + scatter (R12/R16-proven bytes: fp32 Q . ck per head,
// strict-> scan == jax tie-break; rank k packed into qlist bits 11..13).
// ---------------------------------------------------------------------------
__global__ __launch_bounds__(256) void sims_topk(const float* __restrict__ Q,
                                                 const float* __restrict__ ck,
                                                 int* __restrict__ cur,
                                                 unsigned short* __restrict__ qlist) {
    __shared__ float qtile[64][68];
    __shared__ float cks[32][68];
    __shared__ float simsb[64][36];
    __shared__ int   lds_cnt[32];
    __shared__ int   lds_base[32];

    const int t  = threadIdx.x;
    const int s0 = blockIdx.x * 64;
    const int h  = blockIdx.y;

    if (t < 32) lds_cnt[t] = 0;

    {
        int r = t >> 2;
        #pragma unroll
        for (int i = 0; i < 4; ++i) {
            int cf4 = (t & 3) * 4 + i;
            *(float4*)&qtile[r][cf4 * 4] =
                *(const float4*)&Q[(size_t)(s0 + r) * D_DIM + h * HD + cf4 * 4];
        }
    }
    for (int i = t; i < C_NUM * 16; i += 256) {
        int c = i >> 4, df4 = i & 15;
        *(float4*)&cks[c][df4 * 4] =
            *(const float4*)&ck[(size_t)c * D_DIM + h * HD + df4 * 4];
    }
    __syncthreads();

    {
        const int sl = t >> 2, g = t & 3;
        float sa[8] = {0.f,0.f,0.f,0.f,0.f,0.f,0.f,0.f};
        #pragma unroll
        for (int d4 = 0; d4 < 16; ++d4) {
            float4 q4 = *(const float4*)&qtile[sl][d4 * 4];
            #pragma unroll
            for (int j = 0; j < 8; ++j) {
                float4 c4 = *(const float4*)&cks[g * 8 + j][d4 * 4];
                sa[j] += q4.x*c4.x + q4.y*c4.y + q4.z*c4.z + q4.w*c4.w;
            }
        }
        *(float4*)&simsb[sl][g*8 + 0] = make_float4(sa[0], sa[1], sa[2], sa[3]);
        *(float4*)&simsb[sl][g*8 + 4] = make_float4(sa[4], sa[5], sa[6], sa[7]);
    }
    __syncthreads();

    int csel[TOPK], lpos[TOPK];
    if (t < 64) {
        float sv[32];
        #pragma unroll
        for (int cq = 0; cq < 8; ++cq) {
            float4 v = *(const float4*)&simsb[t][cq * 4];
            sv[cq*4+0] = v.x; sv[cq*4+1] = v.y; sv[cq*4+2] = v.z; sv[cq*4+3] = v.w;
        }
        #pragma unroll
        for (int k = 0; k < TOPK; ++k) {
            float best = -INFINITY; int bi = 0;
            #pragma unroll
            for (int cc = 0; cc < 32; ++cc) {
                bool gt = sv[cc] > best;
                best = gt ? sv[cc] : best;
                bi   = gt ? cc : bi;
            }
            #pragma unroll
            for (int cc = 0; cc < 32; ++cc)
                if (cc == bi) sv[cc] = -INFINITY;
            csel[k] = bi;
            lpos[k] = atomicAdd(&lds_cnt[bi], 1);
        }
    }
    __syncthreads();

    if (t < 32) lds_base[t] = atomicAdd(&cur[h * 32 + t], lds_cnt[t]);
    __syncthreads();

    if (t < 64) {
        #pragma unroll
        for (int k = 0; k < TOPK; ++k) {
            int c = csel[k];
            int pos = lds_base[c] + lpos[k];
            if (pos < QCAP)
                qlist[(size_t)(h * 32 + c) * QCAP + pos] =
                    (unsigned short)((s0 + t) | (k << 11));
        }
    }
}

// ---------------------------------------------------------------------------
// MFMA chunk-centric attention (v6c, R16 bytes): fp32 Q staging + bf16 K/V.
// One block barrier; unique-writer Opart/lpart stores (no atomics).
// ---------------------------------------------------------------------------
__global__ __launch_bounds__(256) void moc_attn6c(const float* __restrict__ Qf,
                                                  const unsigned short* __restrict__ Kbf,
                                                  const unsigned short* __restrict__ Vbf,
                                                  const int* __restrict__ cnt,
                                                  const unsigned short* __restrict__ qlist,
                                                  float* __restrict__ lpart,
                                                  float* __restrict__ Opart) {
    __shared__ unsigned short Qs[64][72];
    __shared__ unsigned short Ks[64][72];
    __shared__ unsigned short VT[64][72];
    __shared__ unsigned short Ps[64][72];
    __shared__ unsigned short slist[64];

    const int hc = blockIdx.y;
    const int h  = hc >> 5;
    const int c  = hc & 31;
    const int g  = blockIdx.x;
    const int t  = threadIdx.x;

    const int count = min(cnt[hc], QCAP);
    const int base  = g * 64;
    if (base >= count) return;
    const int lim = min(count - base, 64);

    const unsigned short* Kb = Kbf + ((size_t)c * 64) * D_DIM + h * HD;
    const unsigned short* Vb = Vbf + ((size_t)c * 64) * D_DIM + h * HD;
    const unsigned short* list = qlist + (size_t)hc * QCAP + base;

    {
        const int j  = t >> 2;
        const int d0 = (t & 3) * 16;

        const unsigned short* kr = Kb + (size_t)j * D_DIM + d0;
        *(bf16x8*)&Ks[j][d0]     = *(const bf16x8*)&kr[0];
        *(bf16x8*)&Ks[j][d0 + 8] = *(const bf16x8*)&kr[8];

        const unsigned short* vr = Vb + (size_t)j * D_DIM + d0;
        bf16x8 v0 = *(const bf16x8*)&vr[0];
        bf16x8 v1 = *(const bf16x8*)&vr[8];
        #pragma unroll
        for (int i = 0; i < 8; ++i) {
            VT[d0 + i][j]     = (unsigned short)v0[i];
            VT[d0 + 8 + i][j] = (unsigned short)v1[i];
        }

        unsigned short pv = (j < lim) ? list[j] : (unsigned short)0xFFFF;
        if ((t & 3) == 0) slist[j] = pv;
        int s = (pv == 0xFFFF) ? 0 : (int)(pv & 2047);
        const float* qr = Qf + (size_t)s * D_DIM + h * HD + d0;
        float4 q0 = *(const float4*)&qr[0],  q1 = *(const float4*)&qr[4];
        float4 q2 = *(const float4*)&qr[8],  q3 = *(const float4*)&qr[12];
        *(bf16x8*)&Qs[j][d0]     = pack8(q0, q1);
        *(bf16x8*)&Qs[j][d0 + 8] = pack8(q2, q3);
    }
    __syncthreads();

    const int lane = t & 63;
    const int w    = t >> 6;
    const int lr   = lane & 15;
    const int quad = lane >> 4;

    bf16x8 aq0 = *(const bf16x8*)&Qs[w * 16 + lr][quad * 8];
    bf16x8 aq1 = *(const bf16x8*)&Qs[w * 16 + lr][32 + quad * 8];

    f32x4 acc[4];
    #pragma unroll
    for (int kt = 0; kt < 4; ++kt) {
        bf16x8 b0 = *(const bf16x8*)&Ks[kt * 16 + lr][quad * 8];
        bf16x8 b1 = *(const bf16x8*)&Ks[kt * 16 + lr][32 + quad * 8];
        f32x4 z = {0.f, 0.f, 0.f, 0.f};
        z = __builtin_amdgcn_mfma_f32_16x16x32_bf16(aq0, b0, z, 0, 0, 0);
        z = __builtin_amdgcn_mfma_f32_16x16x32_bf16(aq1, b1, z, 0, 0, 0);
        acc[kt] = z;
    }

    unsigned short pb[4][4];
    float dsum[4] = {0.f, 0.f, 0.f, 0.f};
    #pragma unroll
    for (int kt = 0; kt < 4; ++kt) {
        #pragma unroll
        for (int r = 0; r < 4; ++r) {
            unsigned short u = f2b(__expf(acc[kt][r] * SCALE));
            pb[kt][r] = u;
            dsum[r] += b2f(u);
        }
    }
    #pragma unroll
    for (int r = 0; r < 4; ++r) {
        float v = dsum[r];
        v += __shfl_xor(v, 1, 64);
        v += __shfl_xor(v, 2, 64);
        v += __shfl_xor(v, 4, 64);
        v += __shfl_xor(v, 8, 64);
        dsum[r] = v;
    }
    if (lr == 0) {
        #pragma unroll
        for (int r = 0; r < 4; ++r) {
            unsigned short sv = slist[w * 16 + quad * 4 + r];
            if (sv != 0xFFFF) {
                int kk = sv >> 11, s = sv & 2047;
                lpart[((size_t)kk * H_NUM + h) * S_LEN + s] = dsum[r];
            }
        }
    }

    #pragma unroll
    for (int kt = 0; kt < 4; ++kt)
        #pragma unroll
        for (int r = 0; r < 4; ++r)
            Ps[w * 16 + quad * 4 + r][kt * 16 + lr] = pb[kt][r];

    bf16x8 ap0 = *(const bf16x8*)&Ps[w * 16 + lr][quad * 8];
    bf16x8 ap1 = *(const bf16x8*)&Ps[w * 16 + lr][32 + quad * 8];

    #pragma unroll
    for (int dt = 0; dt < 4; ++dt) {
        bf16x8 b0 = *(const bf16x8*)&VT[dt * 16 + lr][quad * 8];
        bf16x8 b1 = *(const bf16x8*)&VT[dt * 16 + lr][32 + quad * 8];
        f32x4 z = {0.f, 0.f, 0.f, 0.f};
        z = __builtin_amdgcn_mfma_f32_16x16x32_bf16(ap0, b0, z, 0, 0, 0);
        z = __builtin_amdgcn_mfma_f32_16x16x32_bf16(ap1, b1, z, 0, 0, 0);
        #pragma unroll
        for (int r = 0; r < 4; ++r) {
            unsigned short sv = slist[w * 16 + quad * 4 + r];
            if (sv != 0xFFFF) {
                int kk = sv >> 11, s = sv & 2047;
                Opart[((((size_t)kk * H_NUM + h) * S_LEN + s) * HD) + dt * 16 + lr] = z[r];
            }
        }
    }
}

// ---------------------------------------------------------------------------
// Obn_bf[s][h*64+d] = bf16( (sum_k Opart[k][h][s][d]) / (sum_k lpart) )
// ---------------------------------------------------------------------------
__global__ __launch_bounds__(256) void reduce_norm(const float4* __restrict__ Opart4,
                                                   const float* __restrict__ lpart,
                                                   unsigned short* __restrict__ Obn) {
    int i = blockIdx.x * 256 + threadIdx.x;
    int s    = i >> 7;
    int col4 = i & 127;
    int h    = col4 >> 4;
    int f4   = col4 & 15;
    float4 acc = make_float4(0.f,0.f,0.f,0.f);
    float  den = 0.f;
    #pragma unroll
    for (int k = 0; k < TOPK; ++k) {
        size_t slot = ((size_t)k * H_NUM + h) * S_LEN + s;
        float4 v = Opart4[slot * 16 + f4];
        acc.x += v.x; acc.y += v.y; acc.z += v.z; acc.w += v.w;
        den += lpart[slot];
    }
    float inv = 1.0f / den;
    us4 o;
    o[0] = f2b(acc.x * inv); o[1] = f2b(acc.y * inv);
    o[2] = f2b(acc.z * inv); o[3] = f2b(acc.w * inv);
    *(us4*)&Obn[(size_t)i * 4] = o;
}

// ---------------------------------------------------------------------------
// Output projection: bf16 A (normalized attention out), fp32 C (MFMA).
// ---------------------------------------------------------------------------
__global__ __launch_bounds__(256) void gemm_out(const unsigned short* __restrict__ Obn,
                                                const float* __restrict__ Wo,
                                                float* __restrict__ out) {
    __shared__ unsigned short As[64][72];
    __shared__ unsigned short Bs[64][72];

    const int t  = threadIdx.x;
    const int m0 = blockIdx.y * 64;
    const int n0 = blockIdx.x * 64;
    const int rl = t >> 2;
    const int c4 = (t & 3) * 16;
    const int N = D_DIM, K = D_DIM;

    const int lane = t & 63, w = t >> 6, lr = lane & 15, quad = lane >> 4;

    f32x4 acc[4] = {{0.f,0.f,0.f,0.f},{0.f,0.f,0.f,0.f},
                    {0.f,0.f,0.f,0.f},{0.f,0.f,0.f,0.f}};

    bf16x8 ba[2]; float4 fb[4];
    auto LDA = [&](int k0) {
        const unsigned short* p = &Obn[(size_t)(m0 + rl) * K + k0 + c4];
        ba[0] = *(const bf16x8*)&p[0];
        ba[1] = *(const bf16x8*)&p[8];
    };
    auto LDB = [&](int k0) {
        const float* p = &Wo[(size_t)(k0 + rl) * N + n0 + c4];
        fb[0] = *(const float4*)&p[0];  fb[1] = *(const float4*)&p[4];
        fb[2] = *(const float4*)&p[8];  fb[3] = *(const float4*)&p[12];
    };

    LDA(0); LDB(0);
    for (int k0 = 0; k0 < K; k0 += 64) {
        __syncthreads();
        *(bf16x8*)&As[rl][c4]     = ba[0];
        *(bf16x8*)&As[rl][c4 + 8] = ba[1];
        #pragma unroll
        for (int f = 0; f < 4; ++f) {
            float4 v = fb[f];
            Bs[c4 + f*4 + 0][rl] = f2b(v.x);
            Bs[c4 + f*4 + 1][rl] = f2b(v.y);
            Bs[c4 + f*4 + 2][rl] = f2b(v.z);
            Bs[c4 + f*4 + 3][rl] = f2b(v.w);
        }
        __syncthreads();

        if (k0 + 64 < K) { LDA(k0 + 64); LDB(k0 + 64); }

        bf16x8 a0 = *(const bf16x8*)&As[w * 16 + lr][quad * 8];
        bf16x8 a1 = *(const bf16x8*)&As[w * 16 + lr][32 + quad * 8];
        #pragma unroll
        for (int nt = 0; nt < 4; ++nt) {
            bf16x8 b0 = *(const bf16x8*)&Bs[nt * 16 + lr][quad * 8];
            bf16x8 b1 = *(const bf16x8*)&Bs[nt * 16 + lr][32 + quad * 8];
            acc[nt] = __builtin_amdgcn_mfma_f32_16x16x32_bf16(a0, b0, acc[nt], 0, 0, 0);
            acc[nt] = __builtin_amdgcn_mfma_f32_16x16x32_bf16(a1, b1, acc[nt], 0, 0, 0);
        }
    }

    #pragma unroll
    for (int nt = 0; nt < 4; ++nt)
        #pragma unroll
        for (int r = 0; r < 4; ++r) {
            int m = m0 + w * 16 + quad * 4 + r;
            int n = n0 + nt * 16 + lr;
            out[(size_t)m * N + n] = acc[nt][r];
        }
}

// ---------------------------------------------------------------------------
// Workspace (~29 MB):
//   Qf fp32 4MB (reused as Obn bf16 after attention) | Kbf 2MB | Vbf 2MB
//   | ck 64KB | lpart 320KB | cur 1KB | qlist 512KB | Opart 20MB
// ---------------------------------------------------------------------------
extern "C" void kernel_launch(void* const* d_in, const int* in_sizes, int n_in,
                              void* d_out, int out_size, void* d_ws, size_t ws_size,
                              hipStream_t stream) {
    const float* x  = (const float*)d_in[0];
    const float* Wq = (const float*)d_in[1];
    const float* Wk = (const float*)d_in[2];
    const float* Wv = (const float*)d_in[3];
    const float* Wo = (const float*)d_in[4];
    float* out = (float*)d_out;

    const size_t SD = (size_t)S_LEN * D_DIM;   // 1048576
    float* Qf = (float*)d_ws;                              // [2048][512] fp32
    unsigned short* Kbf = (unsigned short*)(Qf + SD);      // [2048][512] bf16
    unsigned short* Vbf = Kbf + SD;                        // [2048][512] bf16
    float* ck   = (float*)(Vbf + SD);                      // [32][512]
    float* lpart = ck + (size_t)C_NUM * D_DIM;             // [5][8][2048]
    int*   curb  = (int*)(lpart + (size_t)TOPK * H_NUM * S_LEN);   // [256]
    unsigned short* qlst = (unsigned short*)(curb + 256);          // [256][QCAP]
    float* Opart = (float*)(qlst + (size_t)256 * QCAP);            // [5][8][2048][64]
    unsigned short* Obn = (unsigned short*)Qf;             // reuse after attention

    dim3 qgrid(D_DIM / BN, S_LEN / BM);          // (8, 32): Q fp32, solo kernel
    gemm_q<<<qgrid, 256, 0, stream>>>(x, Wq, Qf);

    dim3 kvgrid(D_DIM / 64, S_LEN / 64, 3);      // K,V bf16 MFMA + ck/cur (z=2)
    gemm_kv_ck<<<kvgrid, 256, 0, stream>>>(x, Wk, Wv, Kbf, Vbf, ck, curb);

    dim3 rgrid(S_LEN / 64, H_NUM);               // (32, 8)
    sims_topk<<<rgrid, 256, 0, stream>>>(Qf, ck, curb, qlst);

    dim3 agrid(ATILES, H_NUM * C_NUM);           // (16, 256); empties exit
    moc_attn6c<<<agrid, 256, 0, stream>>>(Qf, Kbf, Vbf, curb, qlst, lpart, Opart);

    reduce_norm<<<(int)(SD / 4 / 256), 256, 0, stream>>>((const float4*)Opart, lpart, Obn);

    dim3 ogrid(D_DIM / 64, S_LEN / 64);
    gemm_out<<<ogrid, 256, 0, stream>>>(Obn, Wo, out);
}